// Round 1
// baseline (3812.626 us; speedup 1.0000x reference)
//
#include <hip/hip_runtime.h>

#define N_NODES 100000
#define N_EDGESC 800000
#define HID 128
#define NGRAPH 128
#define BN_EPS 1e-5f

// ---------------- scatter-add over edges: out[dst] += X[src] ----------------
__global__ __launch_bounds__(256) void k_scatter(const float* __restrict__ X,
    const int* __restrict__ src, const int* __restrict__ dst,
    float* __restrict__ out)
{
    int tid = blockIdx.x * 256 + threadIdx.x;
    int e = tid >> 5;            // 32 float4 chunks per 128-feat row
    if (e >= N_EDGESC) return;
    int c = tid & 31;
    int s = src[e], d = dst[e];
    float4 v = ((const float4*)(X + (size_t)s * HID))[c];
    float* o = out + (size_t)d * HID + (size_t)c * 4;
    atomicAdd(o + 0, v.x);
    atomicAdd(o + 1, v.y);
    atomicAdd(o + 2, v.z);
    atomicAdd(o + 3, v.w);
}

// ------------- C[M,128] = act((X1 (+X2)) @ W + b), K=N=128 -----------------
// Block tile: 64 rows x 128 cols, 256 threads, thread tile 8 rows x 4 cols.
// Hs: full-K 64x128 fp32 (32KB). Ws: staged in two K-halves (32KB). 64KB LDS.
// In-place safe (C==X1): block reads all its rows into LDS before writing.
__global__ __launch_bounds__(256) void k_gemm(const float* __restrict__ X1,
    const float* __restrict__ X2, const float* __restrict__ W,
    const float* __restrict__ bias, float* __restrict__ C, int M, int relu)
{
    __shared__ float Hs[64][128];
    __shared__ float Ws[64][128];
    const int t = threadIdx.x;
    const int row0 = blockIdx.x * 64;

    // stage H tile (with optional elementwise add), 8 float4 per thread
    for (int i = t; i < 64 * 32; i += 256) {
        int r = i >> 5, c4 = i & 31;
        float4 v = make_float4(0.f, 0.f, 0.f, 0.f);
        if (row0 + r < M) {
            v = ((const float4*)(X1 + (size_t)(row0 + r) * HID))[c4];
            if (X2) {
                float4 u = ((const float4*)(X2 + (size_t)(row0 + r) * HID))[c4];
                v.x += u.x; v.y += u.y; v.z += u.z; v.w += u.w;
            }
        }
        ((float4*)&Hs[r][0])[c4] = v;
    }

    const int cg = t & 31;   // cols cg*4 .. cg*4+3
    const int rg = t >> 5;   // rows rg*8 .. rg*8+7
    float acc[8][4];
    #pragma unroll
    for (int i = 0; i < 8; ++i)
        #pragma unroll
        for (int j = 0; j < 4; ++j) acc[i][j] = 0.f;

    for (int kb = 0; kb < 128; kb += 64) {
        __syncthreads();   // covers Hs staging (1st iter) and Ws reuse (2nd)
        for (int i = t; i < 64 * 32; i += 256)
            ((float4*)&Ws[0][0])[i] = ((const float4*)(W + (size_t)kb * HID))[i];
        __syncthreads();

        for (int k0 = 0; k0 < 64; k0 += 4) {
            float4 h[8], w[4];
            #pragma unroll
            for (int i = 0; i < 8; ++i)
                h[i] = *(const float4*)&Hs[rg * 8 + i][kb + k0];
            #pragma unroll
            for (int j = 0; j < 4; ++j)
                w[j] = *(const float4*)&Ws[k0 + j][cg * 4];
            #pragma unroll
            for (int i = 0; i < 8; ++i) {
                acc[i][0] += h[i].x*w[0].x + h[i].y*w[1].x + h[i].z*w[2].x + h[i].w*w[3].x;
                acc[i][1] += h[i].x*w[0].y + h[i].y*w[1].y + h[i].z*w[2].y + h[i].w*w[3].y;
                acc[i][2] += h[i].x*w[0].z + h[i].y*w[1].z + h[i].z*w[2].z + h[i].w*w[3].z;
                acc[i][3] += h[i].x*w[0].w + h[i].y*w[1].w + h[i].z*w[2].w + h[i].w*w[3].w;
            }
        }
    }

    float4 bv = *(const float4*)&bias[cg * 4];
    #pragma unroll
    for (int i = 0; i < 8; ++i) {
        int r = row0 + rg * 8 + i;
        if (r < M) {
            float4 o;
            o.x = acc[i][0] + bv.x; o.y = acc[i][1] + bv.y;
            o.z = acc[i][2] + bv.z; o.w = acc[i][3] + bv.w;
            if (relu) {
                o.x = fmaxf(o.x, 0.f); o.y = fmaxf(o.y, 0.f);
                o.z = fmaxf(o.z, 0.f); o.w = fmaxf(o.w, 0.f);
            }
            ((float4*)(C + (size_t)r * HID))[cg] = o;
        }
    }
}

// ---------------- BN: per-feature sum / sumsq ----------------
__global__ __launch_bounds__(256) void k_bnstats(const float* __restrict__ X,
    float* __restrict__ S, int M)
{
    int f = threadIdx.x & 127;
    int half = threadIdx.x >> 7;
    float s = 0.f, s2 = 0.f;
    for (int r = blockIdx.x * 2 + half; r < M; r += gridDim.x * 2) {
        float v = X[(size_t)r * HID + f];
        s += v; s2 += v * v;
    }
    atomicAdd(&S[f], s);
    atomicAdd(&S[HID + f], s2);
}

__global__ void k_bnfinalize(const float* __restrict__ S,
    const float* __restrict__ gamma, const float* __restrict__ beta,
    float* __restrict__ SC, int M)
{
    int f = threadIdx.x;  // 128
    float mean = S[f] / (float)M;
    float var = S[HID + f] / (float)M - mean * mean;
    var = fmaxf(var, 0.f);
    float sc = gamma[f] * rsqrtf(var + BN_EPS);
    SC[f] = sc;
    SC[HID + f] = beta[f] - mean * sc;
}

__global__ __launch_bounds__(256) void k_bnapply(const float* __restrict__ X,
    const float* __restrict__ SC, float* __restrict__ Y, int M)
{
    int idx = blockIdx.x * 256 + threadIdx.x;   // float4 index
    if (idx >= M * 32) return;
    int c4 = idx & 31;
    float4 v = ((const float4*)X)[idx];
    float4 sc = ((const float4*)SC)[c4];
    float4 sh = ((const float4*)SC)[32 + c4];
    float4 o;
    o.x = fmaxf(v.x * sc.x + sh.x, 0.f);
    o.y = fmaxf(v.y * sc.y + sh.y, 0.f);
    o.z = fmaxf(v.z * sc.z + sh.z, 0.f);
    o.w = fmaxf(v.w * sc.w + sh.w, 0.f);
    ((float4*)Y)[idx] = o;
}

// ---------------- per-graph mean pool (sums + counts) ----------------
__global__ __launch_bounds__(256) void k_pool(const float* __restrict__ H,
    const int* __restrict__ batch, float* __restrict__ P, float* __restrict__ CNT)
{
    int idx = blockIdx.x * 256 + threadIdx.x;
    if (idx >= N_NODES * HID) return;
    int n = idx >> 7, f = idx & 127;
    int g = batch[n];
    atomicAdd(&P[(size_t)g * HID + f], H[idx]);
    if (f == 0) atomicAdd(&CNT[g], 1.f);
}

// ---------------- classifier head + log_softmax ----------------
__global__ void k_head(const float* __restrict__ P, const float* __restrict__ CNT,
    const float* __restrict__ Wlin, const float* __restrict__ blin,
    float* __restrict__ out)
{
    int g = blockIdx.x;     // 128 graphs
    int l = threadIdx.x;    // 64 lanes = 1 wave
    float inv = 1.f / fmaxf(CNT[g], 1.f);
    float p0 = P[(size_t)g * HID + l] * inv;
    float p1 = P[(size_t)g * HID + 64 + l] * inv;
    float lg[10];
    #pragma unroll
    for (int c = 0; c < 10; ++c) {
        float v = p0 * Wlin[l * 10 + c] + p1 * Wlin[(64 + l) * 10 + c];
        #pragma unroll
        for (int off = 32; off > 0; off >>= 1) v += __shfl_down(v, off);
        lg[c] = v;
    }
    if (l == 0) {
        float mx = -1e30f;
        #pragma unroll
        for (int c = 0; c < 10; ++c) { lg[c] += blin[c]; mx = fmaxf(mx, lg[c]); }
        float s = 0.f;
        #pragma unroll
        for (int c = 0; c < 10; ++c) s += expf(lg[c] - mx);
        float lse = mx + logf(s);
        #pragma unroll
        for (int c = 0; c < 10; ++c) out[g * 10 + c] = lg[c] - lse;
    }
}

extern "C" void kernel_launch(void* const* d_in, const int* in_sizes, int n_in,
                              void* d_out, int out_size, void* d_ws, size_t ws_size,
                              hipStream_t stream)
{
    const float* x    = (const float*)d_in[0];
    const int*   ei   = (const int*)d_in[1];     // [2, E] int32
    const int*   batch= (const int*)d_in[2];
    const float* W1a  = (const float*)d_in[3];
    const float* b1a  = (const float*)d_in[4];
    const float* W1b  = (const float*)d_in[5];
    const float* b1b  = (const float*)d_in[6];
    const float* g1   = (const float*)d_in[7];
    const float* be1  = (const float*)d_in[8];
    const float* W2a  = (const float*)d_in[9];
    const float* b2a  = (const float*)d_in[10];
    const float* W2b  = (const float*)d_in[11];
    const float* b2b  = (const float*)d_in[12];
    const float* g2   = (const float*)d_in[13];
    const float* be2  = (const float*)d_in[14];
    const float* Wl   = (const float*)d_in[15];
    const float* bl   = (const float*)d_in[16];
    float* out = (float*)d_out;

    float* ws = (float*)d_ws;
    const size_t NM = (size_t)N_NODES * HID;    // 12.8M floats
    float* A   = ws;                 // agg1 -> h1(normed) -> h2(normed)
    float* B   = ws + NM;            // MLP hidden / conv2 pre-BN
    float* C   = ws + 2 * NM;        // conv1 pre-BN / agg2
    float* S   = ws + 3 * NM;        // 256: sum, sumsq
    float* SC  = S + 256;            // 256: scale, shift
    float* P   = SC + 256;           // 128*128 pooled sums
    float* CNT = P + (size_t)NGRAPH * HID;  // 128 counts

    const int* src = ei;
    const int* dst = ei + N_EDGESC;

    // zero scratch accumulators (ws is poisoned before every call)
    hipMemsetAsync(A, 0, NM * sizeof(float), stream);
    hipMemsetAsync(S, 0, (256 + 256 + (size_t)NGRAPH * HID + NGRAPH) * sizeof(float), stream);

    dim3 blk(256);
    const int scatterBlocks = (N_EDGESC * 32) / 256;   // 100000
    const int gemmBlocks = (N_NODES + 63) / 64;        // 1563
    const int ewBlocks = (N_NODES * 32) / 256;         // 12500
    const int poolBlocks = (N_NODES * HID) / 256;      // 50000

    // ---- conv1 ----
    k_scatter<<<scatterBlocks, blk, 0, stream>>>(x, src, dst, A);
    k_gemm<<<gemmBlocks, blk, 0, stream>>>(x, A, W1a, b1a, B, N_NODES, 1);
    k_gemm<<<gemmBlocks, blk, 0, stream>>>(B, nullptr, W1b, b1b, C, N_NODES, 0);
    k_bnstats<<<256, blk, 0, stream>>>(C, S, N_NODES);
    k_bnfinalize<<<1, 128, 0, stream>>>(S, g1, be1, SC, N_NODES);
    k_bnapply<<<ewBlocks, blk, 0, stream>>>(C, SC, A, N_NODES);   // A = h1

    // ---- conv2 ----
    hipMemsetAsync(C, 0, NM * sizeof(float), stream);
    hipMemsetAsync(S, 0, 256 * sizeof(float), stream);
    k_scatter<<<scatterBlocks, blk, 0, stream>>>(A, src, dst, C);
    k_gemm<<<gemmBlocks, blk, 0, stream>>>(A, C, W2a, b2a, B, N_NODES, 1);
    k_gemm<<<gemmBlocks, blk, 0, stream>>>(B, nullptr, W2b, b2b, B, N_NODES, 0); // in-place
    k_bnstats<<<256, blk, 0, stream>>>(B, S, N_NODES);
    k_bnfinalize<<<1, 128, 0, stream>>>(S, g2, be2, SC, N_NODES);
    k_bnapply<<<ewBlocks, blk, 0, stream>>>(B, SC, A, N_NODES);   // A = h2

    // ---- pool + head ----
    k_pool<<<poolBlocks, blk, 0, stream>>>(A, batch, P, CNT);
    k_head<<<NGRAPH, 64, 0, stream>>>(P, CNT, Wl, bl, out);
}

// Round 2
// 868.662 us; speedup vs baseline: 4.3891x; 4.3891x over previous
//
#include <hip/hip_runtime.h>

#define N_NODES 100000
#define N_EDGESC 800000
#define HID 128
#define NGRAPH 128
#define BN_EPS 1e-5f
#define SCAN_BLOCKS ((N_NODES + 1023) / 1024)   // 98

// ================= CSR build =================
__global__ __launch_bounds__(256) void k_count(const int* __restrict__ dst,
                                               int* __restrict__ deg)
{
    int e = blockIdx.x * 256 + threadIdx.x;
    if (e < N_EDGESC) atomicAdd(&deg[dst[e]], 1);
}

// block-level exclusive scan: 1024 entries/block (4 per thread)
__global__ __launch_bounds__(256) void k_scan_block(const int* __restrict__ deg,
    int* __restrict__ off, int* __restrict__ bsum)
{
    __shared__ int ts[256];
    int base = blockIdx.x * 1024 + threadIdx.x * 4;
    int v[4], s = 0;
    #pragma unroll
    for (int i = 0; i < 4; ++i) {
        int idx = base + i;
        v[i] = (idx < N_NODES) ? deg[idx] : 0;
        s += v[i];
    }
    ts[threadIdx.x] = s;
    __syncthreads();
    for (int d = 1; d < 256; d <<= 1) {
        int t = (threadIdx.x >= d) ? ts[threadIdx.x - d] : 0;
        __syncthreads();
        ts[threadIdx.x] += t;
        __syncthreads();
    }
    int run = ts[threadIdx.x] - s;   // exclusive prefix within block
    #pragma unroll
    for (int i = 0; i < 4; ++i) {
        int idx = base + i;
        if (idx < N_NODES) off[idx] = run;
        run += v[i];
    }
    if (threadIdx.x == 255) bsum[blockIdx.x] = ts[255];
}

__global__ void k_scan_top(int* __restrict__ bsum, int* __restrict__ off)
{
    int run = 0;
    for (int i = 0; i < SCAN_BLOCKS; ++i) { int t = bsum[i]; bsum[i] = run; run += t; }
    off[N_NODES] = run;   // = N_EDGESC
}

__global__ __launch_bounds__(256) void k_scan_add(int* __restrict__ off,
    const int* __restrict__ bsum, int* __restrict__ cursor)
{
    int i = blockIdx.x * 256 + threadIdx.x;
    if (i < N_NODES) {
        int o = off[i] + bsum[i >> 10];
        off[i] = o;
        cursor[i] = o;
    }
}

__global__ __launch_bounds__(256) void k_fill(const int* __restrict__ src,
    const int* __restrict__ dst, int* __restrict__ cursor, int* __restrict__ eidx)
{
    int e = blockIdx.x * 256 + threadIdx.x;
    if (e < N_EDGESC) {
        int p = atomicAdd(&cursor[dst[e]], 1);
        eidx[p] = src[e];
    }
}

// ============ gather aggregation: OUT[n] = X[n] + sum_{j->n} X[j] ============
// 32-lane group per node (one float4 lane each); 8 nodes per 256-thread block.
__global__ __launch_bounds__(256) void k_aggregate(const float* __restrict__ X,
    const int* __restrict__ off, const int* __restrict__ eidx,
    float* __restrict__ OUT)
{
    int n = blockIdx.x * 8 + (threadIdx.x >> 5);
    if (n >= N_NODES) return;
    int lane = threadIdx.x & 31;
    int beg = off[n], end = off[n + 1];
    float4 acc = ((const float4*)(X + (size_t)n * HID))[lane];
    for (int k = beg; k < end; ++k) {
        int s = eidx[k];
        float4 v = ((const float4*)(X + (size_t)s * HID))[lane];
        acc.x += v.x; acc.y += v.y; acc.z += v.z; acc.w += v.w;
    }
    ((float4*)(OUT + (size_t)n * HID))[lane] = acc;
}

// ------------- C[M,128] = act(X @ W + b), K=N=128, in-place safe -----------
__global__ __launch_bounds__(256) void k_gemm(const float* __restrict__ X,
    const float* __restrict__ W, const float* __restrict__ bias,
    float* __restrict__ C, int M, int relu)
{
    __shared__ float Hs[64][128];
    __shared__ float Ws[64][128];
    const int t = threadIdx.x;
    const int row0 = blockIdx.x * 64;

    for (int i = t; i < 64 * 32; i += 256) {
        int r = i >> 5, c4 = i & 31;
        float4 v = make_float4(0.f, 0.f, 0.f, 0.f);
        if (row0 + r < M)
            v = ((const float4*)(X + (size_t)(row0 + r) * HID))[c4];
        ((float4*)&Hs[r][0])[c4] = v;
    }

    const int cg = t & 31;
    const int rg = t >> 5;
    float acc[8][4];
    #pragma unroll
    for (int i = 0; i < 8; ++i)
        #pragma unroll
        for (int j = 0; j < 4; ++j) acc[i][j] = 0.f;

    for (int kb = 0; kb < 128; kb += 64) {
        __syncthreads();
        for (int i = t; i < 64 * 32; i += 256)
            ((float4*)&Ws[0][0])[i] = ((const float4*)(W + (size_t)kb * HID))[i];
        __syncthreads();

        for (int k0 = 0; k0 < 64; k0 += 4) {
            float4 h[8], w[4];
            #pragma unroll
            for (int i = 0; i < 8; ++i)
                h[i] = *(const float4*)&Hs[rg * 8 + i][kb + k0];
            #pragma unroll
            for (int j = 0; j < 4; ++j)
                w[j] = *(const float4*)&Ws[k0 + j][cg * 4];
            #pragma unroll
            for (int i = 0; i < 8; ++i) {
                acc[i][0] += h[i].x*w[0].x + h[i].y*w[1].x + h[i].z*w[2].x + h[i].w*w[3].x;
                acc[i][1] += h[i].x*w[0].y + h[i].y*w[1].y + h[i].z*w[2].y + h[i].w*w[3].y;
                acc[i][2] += h[i].x*w[0].z + h[i].y*w[1].z + h[i].z*w[2].z + h[i].w*w[3].z;
                acc[i][3] += h[i].x*w[0].w + h[i].y*w[1].w + h[i].z*w[2].w + h[i].w*w[3].w;
            }
        }
    }

    float4 bv = *(const float4*)&bias[cg * 4];
    #pragma unroll
    for (int i = 0; i < 8; ++i) {
        int r = row0 + rg * 8 + i;
        if (r < M) {
            float4 o;
            o.x = acc[i][0] + bv.x; o.y = acc[i][1] + bv.y;
            o.z = acc[i][2] + bv.z; o.w = acc[i][3] + bv.w;
            if (relu) {
                o.x = fmaxf(o.x, 0.f); o.y = fmaxf(o.y, 0.f);
                o.z = fmaxf(o.z, 0.f); o.w = fmaxf(o.w, 0.f);
            }
            ((float4*)(C + (size_t)r * HID))[cg] = o;
        }
    }
}

// ---------------- BN ----------------
__global__ __launch_bounds__(256) void k_bnstats(const float* __restrict__ X,
    float* __restrict__ S, int M)
{
    int f = threadIdx.x & 127;
    int half = threadIdx.x >> 7;
    float s = 0.f, s2 = 0.f;
    for (int r = blockIdx.x * 2 + half; r < M; r += gridDim.x * 2) {
        float v = X[(size_t)r * HID + f];
        s += v; s2 += v * v;
    }
    atomicAdd(&S[f], s);
    atomicAdd(&S[HID + f], s2);
}

__global__ void k_bnfinalize(const float* __restrict__ S,
    const float* __restrict__ gamma, const float* __restrict__ beta,
    float* __restrict__ SC, int M)
{
    int f = threadIdx.x;
    float mean = S[f] / (float)M;
    float var = S[HID + f] / (float)M - mean * mean;
    var = fmaxf(var, 0.f);
    float sc = gamma[f] * rsqrtf(var + BN_EPS);
    SC[f] = sc;
    SC[HID + f] = beta[f] - mean * sc;
}

__global__ __launch_bounds__(256) void k_bnapply(const float* __restrict__ X,
    const float* __restrict__ SC, float* __restrict__ Y, int M)
{
    int idx = blockIdx.x * 256 + threadIdx.x;
    if (idx >= M * 32) return;
    int c4 = idx & 31;
    float4 v = ((const float4*)X)[idx];
    float4 sc = ((const float4*)SC)[c4];
    float4 sh = ((const float4*)SC)[32 + c4];
    float4 o;
    o.x = fmaxf(v.x * sc.x + sh.x, 0.f);
    o.y = fmaxf(v.y * sc.y + sh.y, 0.f);
    o.z = fmaxf(v.z * sc.z + sh.z, 0.f);
    o.w = fmaxf(v.w * sc.w + sh.w, 0.f);
    ((float4*)Y)[idx] = o;
}

// ---------------- pooling via sorted-batch boundaries ----------------
__global__ void k_bounds(const int* __restrict__ batch, int* __restrict__ gstart)
{
    int g = threadIdx.x;   // 0..127
    int lo = 0, hi = N_NODES;
    while (lo < hi) {
        int mid = (lo + hi) >> 1;
        if (batch[mid] < g) lo = mid + 1; else hi = mid;
    }
    gstart[g] = lo;
    if (g == 0) gstart[NGRAPH] = N_NODES;
}

__global__ __launch_bounds__(256) void k_pool(const float* __restrict__ H,
    const int* __restrict__ gstart, float* __restrict__ P)
{
    int g = blockIdx.x;
    int beg = gstart[g], end = gstart[g + 1];
    int f = threadIdx.x & 127, half = threadIdx.x >> 7;
    float s = 0.f;
    for (int r = beg + half; r < end; r += 2)
        s += H[(size_t)r * HID + f];
    __shared__ float ls[256];
    ls[threadIdx.x] = s;
    __syncthreads();
    if (threadIdx.x < 128) {
        float tot = ls[threadIdx.x] + ls[threadIdx.x + 128];
        int cnt = end - beg;
        P[g * HID + threadIdx.x] = tot / (float)max(cnt, 1);
    }
}

// ---------------- classifier head + log_softmax ----------------
__global__ void k_head(const float* __restrict__ P,
    const float* __restrict__ Wlin, const float* __restrict__ blin,
    float* __restrict__ out)
{
    int g = blockIdx.x;
    int l = threadIdx.x;    // 64 lanes
    float p0 = P[(size_t)g * HID + l];
    float p1 = P[(size_t)g * HID + 64 + l];
    float lg[10];
    #pragma unroll
    for (int c = 0; c < 10; ++c) {
        float v = p0 * Wlin[l * 10 + c] + p1 * Wlin[(64 + l) * 10 + c];
        #pragma unroll
        for (int off = 32; off > 0; off >>= 1) v += __shfl_down(v, off);
        lg[c] = v;
    }
    if (l == 0) {
        float mx = -1e30f;
        #pragma unroll
        for (int c = 0; c < 10; ++c) { lg[c] += blin[c]; mx = fmaxf(mx, lg[c]); }
        float s = 0.f;
        #pragma unroll
        for (int c = 0; c < 10; ++c) s += expf(lg[c] - mx);
        float lse = mx + logf(s);
        #pragma unroll
        for (int c = 0; c < 10; ++c) out[g * 10 + c] = lg[c] - lse;
    }
}

extern "C" void kernel_launch(void* const* d_in, const int* in_sizes, int n_in,
                              void* d_out, int out_size, void* d_ws, size_t ws_size,
                              hipStream_t stream)
{
    const float* x    = (const float*)d_in[0];
    const int*   ei   = (const int*)d_in[1];
    const int*   batch= (const int*)d_in[2];
    const float* W1a  = (const float*)d_in[3];
    const float* b1a  = (const float*)d_in[4];
    const float* W1b  = (const float*)d_in[5];
    const float* b1b  = (const float*)d_in[6];
    const float* g1   = (const float*)d_in[7];
    const float* be1  = (const float*)d_in[8];
    const float* W2a  = (const float*)d_in[9];
    const float* b2a  = (const float*)d_in[10];
    const float* W2b  = (const float*)d_in[11];
    const float* b2b  = (const float*)d_in[12];
    const float* g2   = (const float*)d_in[13];
    const float* be2  = (const float*)d_in[14];
    const float* Wl   = (const float*)d_in[15];
    const float* bl   = (const float*)d_in[16];
    float* out = (float*)d_out;

    const int* src = ei;
    const int* dst = ei + N_EDGESC;

    float* ws = (float*)d_ws;
    const size_t NM = (size_t)N_NODES * HID;
    float* A    = ws;                 // NM
    float* B    = ws + NM;            // NM
    float* S    = ws + 2 * NM;        // 256
    float* SC   = S + 256;            // 256
    float* P    = SC + 256;           // 128*128
    int* deg    = (int*)(P + (size_t)NGRAPH * HID);
    int* off    = deg + N_NODES;          // N_NODES+1
    int* cursor = off + N_NODES + 1;      // N_NODES
    int* bsum   = cursor + N_NODES;       // SCAN_BLOCKS
    int* eidx   = bsum + SCAN_BLOCKS;     // N_EDGESC
    int* gstart = eidx + N_EDGESC;        // NGRAPH+1

    dim3 blk(256);
    const int edgeBlocks = (N_EDGESC + 255) / 256;     // 3125
    const int nodeBlocks = (N_NODES + 255) / 256;      // 391
    const int gemmBlocks = (N_NODES + 63) / 64;        // 1563
    const int ewBlocks = (N_NODES * 32) / 256;         // 12500
    const int aggBlocks = (N_NODES + 7) / 8;           // 12500

    // ---- CSR build (once; reused by both convs) ----
    hipMemsetAsync(deg, 0, N_NODES * sizeof(int), stream);
    k_count<<<edgeBlocks, blk, 0, stream>>>(dst, deg);
    k_scan_block<<<SCAN_BLOCKS, blk, 0, stream>>>(deg, off, bsum);
    k_scan_top<<<1, 1, 0, stream>>>(bsum, off);
    k_scan_add<<<nodeBlocks, blk, 0, stream>>>(off, bsum, cursor);
    k_fill<<<edgeBlocks, blk, 0, stream>>>(src, dst, cursor, eidx);
    k_bounds<<<1, 128, 0, stream>>>(batch, gstart);

    // ---- conv1 ----
    k_aggregate<<<aggBlocks, blk, 0, stream>>>(x, off, eidx, A);
    k_gemm<<<gemmBlocks, blk, 0, stream>>>(A, W1a, b1a, B, N_NODES, 1);
    k_gemm<<<gemmBlocks, blk, 0, stream>>>(B, W1b, b1b, B, N_NODES, 0);  // in-place
    hipMemsetAsync(S, 0, 256 * sizeof(float), stream);
    k_bnstats<<<256, blk, 0, stream>>>(B, S, N_NODES);
    k_bnfinalize<<<1, 128, 0, stream>>>(S, g1, be1, SC, N_NODES);
    k_bnapply<<<ewBlocks, blk, 0, stream>>>(B, SC, A, N_NODES);   // A = h1

    // ---- conv2 ----
    k_aggregate<<<aggBlocks, blk, 0, stream>>>(A, off, eidx, B);
    k_gemm<<<gemmBlocks, blk, 0, stream>>>(B, W2a, b2a, B, N_NODES, 1);  // in-place
    k_gemm<<<gemmBlocks, blk, 0, stream>>>(B, W2b, b2b, B, N_NODES, 0);  // in-place
    hipMemsetAsync(S, 0, 256 * sizeof(float), stream);
    k_bnstats<<<256, blk, 0, stream>>>(B, S, N_NODES);
    k_bnfinalize<<<1, 128, 0, stream>>>(S, g2, be2, SC, N_NODES);
    k_bnapply<<<ewBlocks, blk, 0, stream>>>(B, SC, A, N_NODES);   // A = h2

    // ---- pool + head ----
    k_pool<<<NGRAPH, blk, 0, stream>>>(A, gstart, P);
    k_head<<<NGRAPH, 64, 0, stream>>>(P, Wl, bl, out);
}

// Round 3
// 664.978 us; speedup vs baseline: 5.7335x; 1.3063x over previous
//
#include <hip/hip_runtime.h>

#define N_NODES 100000
#define N_EDGESC 800000
#define HID 128
#define NGRAPH 128
#define BN_EPS 1e-5f
#define SCAN_BLOCKS ((N_NODES + 1023) / 1024)   // 98

typedef __bf16 bf16x8 __attribute__((ext_vector_type(8)));
typedef float f32x4 __attribute__((ext_vector_type(4)));

__device__ inline unsigned short f2bf(float f) {     // RNE fp32 -> bf16
    unsigned int u = __float_as_uint(f);
    unsigned int r = u + 0x7FFFu + ((u >> 16) & 1u);
    return (unsigned short)(r >> 16);
}
__device__ inline float b2f(unsigned short u) {
    return __uint_as_float(((unsigned int)u) << 16);
}

// ================= CSR build =================
__global__ __launch_bounds__(256) void k_count(const int* __restrict__ dst,
                                               int* __restrict__ deg)
{
    int e = blockIdx.x * 256 + threadIdx.x;
    if (e < N_EDGESC) atomicAdd(&deg[dst[e]], 1);
}

__global__ __launch_bounds__(256) void k_scan_block(const int* __restrict__ deg,
    int* __restrict__ off, int* __restrict__ bsum)
{
    __shared__ int ts[256];
    int base = blockIdx.x * 1024 + threadIdx.x * 4;
    int v[4], s = 0;
    #pragma unroll
    for (int i = 0; i < 4; ++i) {
        int idx = base + i;
        v[i] = (idx < N_NODES) ? deg[idx] : 0;
        s += v[i];
    }
    ts[threadIdx.x] = s;
    __syncthreads();
    for (int d = 1; d < 256; d <<= 1) {
        int t = (threadIdx.x >= d) ? ts[threadIdx.x - d] : 0;
        __syncthreads();
        ts[threadIdx.x] += t;
        __syncthreads();
    }
    int run = ts[threadIdx.x] - s;
    #pragma unroll
    for (int i = 0; i < 4; ++i) {
        int idx = base + i;
        if (idx < N_NODES) off[idx] = run;
        run += v[i];
    }
    if (threadIdx.x == 255) bsum[blockIdx.x] = ts[255];
}

__global__ void k_scan_top(int* __restrict__ bsum, int* __restrict__ off)
{
    int run = 0;
    for (int i = 0; i < SCAN_BLOCKS; ++i) { int t = bsum[i]; bsum[i] = run; run += t; }
    off[N_NODES] = run;
}

__global__ __launch_bounds__(256) void k_scan_add(int* __restrict__ off,
    const int* __restrict__ bsum, int* __restrict__ cursor)
{
    int i = blockIdx.x * 256 + threadIdx.x;
    if (i < N_NODES) {
        int o = off[i] + bsum[i >> 10];
        off[i] = o;
        cursor[i] = o;
    }
}

__global__ __launch_bounds__(256) void k_fill(const int* __restrict__ src,
    const int* __restrict__ dst, int* __restrict__ cursor, int* __restrict__ eidx)
{
    int e = blockIdx.x * 256 + threadIdx.x;
    if (e < N_EDGESC) {
        int p = atomicAdd(&cursor[dst[e]], 1);
        eidx[p] = src[e];
    }
}

// ================ dtype conversion ================
__global__ __launch_bounds__(256) void k_cvt(const float* __restrict__ X,
    unsigned short* __restrict__ Y, int n4)
{
    int i = blockIdx.x * 256 + threadIdx.x;
    if (i < n4) {
        float4 v = ((const float4*)X)[i];
        ((ushort4*)Y)[i] = make_ushort4(f2bf(v.x), f2bf(v.y), f2bf(v.z), f2bf(v.w));
    }
}

// convert + transpose one 128x128 weight: WT[n][k] = bf16(W[k][n])
__global__ __launch_bounds__(256) void k_wcvt(const float* __restrict__ W,
    unsigned short* __restrict__ WT)
{
    int idx = blockIdx.x * 256 + threadIdx.x;   // 64 blocks
    int k = idx >> 7, n = idx & 127;
    WT[n * 128 + k] = f2bf(W[idx]);
}

// ======== gather aggregation (bf16): OUT[n] = X[n] + sum_{j->n} X[j] ========
// 32-lane group per node, ushort4 (8B) per lane = 256B/row.
__global__ __launch_bounds__(256) void k_aggregate(const unsigned short* __restrict__ X,
    const int* __restrict__ off, const int* __restrict__ eidx,
    unsigned short* __restrict__ OUT)
{
    int n = blockIdx.x * 8 + (threadIdx.x >> 5);
    if (n >= N_NODES) return;
    int lane = threadIdx.x & 31;
    int beg = off[n], end = off[n + 1];
    ushort4 o = ((const ushort4*)(X + (size_t)n * HID))[lane];
    float ax = b2f(o.x), ay = b2f(o.y), az = b2f(o.z), aw = b2f(o.w);
    for (int k = beg; k < end; ++k) {
        int s = eidx[k];
        ushort4 v = ((const ushort4*)(X + (size_t)s * HID))[lane];
        ax += b2f(v.x); ay += b2f(v.y); az += b2f(v.z); aw += b2f(v.w);
    }
    ((ushort4*)(OUT + (size_t)n * HID))[lane] =
        make_ushort4(f2bf(ax), f2bf(ay), f2bf(az), f2bf(aw));
}

// ============== MFMA GEMM: C[M,128] = act(A @ W + b), K=128 ==============
// No LDS: A-frags direct from global bf16; B-frags from WT[n][k] (32KB, L1-hot).
// Block = 4 waves x 16 rows = 64 rows. Per wave: 8 n-tiles x 4 k-steps = 32 MFMAs.
__global__ __launch_bounds__(256) void k_gemm_mfma(const unsigned short* __restrict__ A,
    const unsigned short* __restrict__ WT, const float* __restrict__ bias,
    float* __restrict__ Cf, unsigned short* __restrict__ Cb, int M, int relu)
{
    const int tid = threadIdx.x;
    const int wave = tid >> 6;
    const int lane = tid & 63;
    const int m = lane & 15;          // A row / D col within tile
    const int quad = lane >> 4;       // k-subrange selector; D row group
    const int base = blockIdx.x * 64 + wave * 16;

    f32x4 acc[8];
    #pragma unroll
    for (int n0 = 0; n0 < 8; ++n0) acc[n0] = {0.f, 0.f, 0.f, 0.f};

    const unsigned short* arow = A + (size_t)(base + m) * HID + quad * 8;
    const unsigned short* wrow = WT + (size_t)m * HID + quad * 8;

    #pragma unroll
    for (int kk = 0; kk < 4; ++kk) {
        bf16x8 a = *(const bf16x8*)(arow + kk * 32);
        #pragma unroll
        for (int n0 = 0; n0 < 8; ++n0) {
            bf16x8 b = *(const bf16x8*)(wrow + (size_t)n0 * 16 * HID + kk * 32);
            acc[n0] = __builtin_amdgcn_mfma_f32_16x16x32_bf16(a, b, acc[n0], 0, 0, 0);
        }
    }

    #pragma unroll
    for (int n0 = 0; n0 < 8; ++n0) {
        float bv = bias[n0 * 16 + m];
        #pragma unroll
        for (int r = 0; r < 4; ++r) {
            int row = base + quad * 4 + r;
            if (row < M) {
                float v = acc[n0][r] + bv;
                if (relu) v = fmaxf(v, 0.f);
                if (Cf) Cf[(size_t)row * HID + n0 * 16 + m] = v;
                else    Cb[(size_t)row * HID + n0 * 16 + m] = f2bf(v);
            }
        }
    }
}

// ---------------- BN ----------------
__global__ __launch_bounds__(256) void k_bnstats(const float* __restrict__ X,
    float* __restrict__ S, int M)
{
    int f = threadIdx.x & 127;
    int half = threadIdx.x >> 7;
    float s = 0.f, s2 = 0.f;
    for (int r = blockIdx.x * 2 + half; r < M; r += gridDim.x * 2) {
        float v = X[(size_t)r * HID + f];
        s += v; s2 += v * v;
    }
    atomicAdd(&S[f], s);
    atomicAdd(&S[HID + f], s2);
}

__global__ void k_bnfinalize(const float* __restrict__ S,
    const float* __restrict__ gamma, const float* __restrict__ beta,
    float* __restrict__ SC, int M)
{
    int f = threadIdx.x;
    float mean = S[f] / (float)M;
    float var = S[HID + f] / (float)M - mean * mean;
    var = fmaxf(var, 0.f);
    float sc = gamma[f] * rsqrtf(var + BN_EPS);
    SC[f] = sc;
    SC[HID + f] = beta[f] - mean * sc;
}

// BN apply + ReLU, fp32 in -> bf16 out
__global__ __launch_bounds__(256) void k_bnapply(const float* __restrict__ X,
    const float* __restrict__ SC, unsigned short* __restrict__ Y, int M)
{
    int idx = blockIdx.x * 256 + threadIdx.x;   // float4 groups
    if (idx >= M * 32) return;
    int c4 = idx & 31;
    float4 v = ((const float4*)X)[idx];
    float4 sc = ((const float4*)SC)[c4];
    float4 sh = ((const float4*)SC)[32 + c4];
    ((ushort4*)Y)[idx] = make_ushort4(
        f2bf(fmaxf(v.x * sc.x + sh.x, 0.f)),
        f2bf(fmaxf(v.y * sc.y + sh.y, 0.f)),
        f2bf(fmaxf(v.z * sc.z + sh.z, 0.f)),
        f2bf(fmaxf(v.w * sc.w + sh.w, 0.f)));
}

// ---------------- pooling ----------------
__global__ void k_bounds(const int* __restrict__ batch, int* __restrict__ gstart)
{
    int g = threadIdx.x;
    int lo = 0, hi = N_NODES;
    while (lo < hi) {
        int mid = (lo + hi) >> 1;
        if (batch[mid] < g) lo = mid + 1; else hi = mid;
    }
    gstart[g] = lo;
    if (g == 0) gstart[NGRAPH] = N_NODES;
}

// 16 blocks per graph; partial sums via atomics into P (sums, not means)
__global__ __launch_bounds__(256) void k_pool(const unsigned short* __restrict__ H,
    const int* __restrict__ gstart, float* __restrict__ P)
{
    int g = blockIdx.x >> 4, part = blockIdx.x & 15;
    int beg = gstart[g], end = gstart[g + 1];
    int f = threadIdx.x & 127, half = threadIdx.x >> 7;
    float s = 0.f;
    for (int r = beg + part * 2 + half; r < end; r += 32)
        s += b2f(H[(size_t)r * HID + f]);
    __shared__ float ls[256];
    ls[threadIdx.x] = s;
    __syncthreads();
    if (threadIdx.x < 128)
        atomicAdd(&P[g * HID + threadIdx.x], ls[threadIdx.x] + ls[threadIdx.x + 128]);
}

// ---------------- classifier head + log_softmax ----------------
__global__ void k_head(const float* __restrict__ P, const int* __restrict__ gstart,
    const float* __restrict__ Wlin, const float* __restrict__ blin,
    float* __restrict__ out)
{
    int g = blockIdx.x;
    int l = threadIdx.x;    // 64 lanes
    float inv = 1.f / (float)max(gstart[g + 1] - gstart[g], 1);
    float p0 = P[(size_t)g * HID + l] * inv;
    float p1 = P[(size_t)g * HID + 64 + l] * inv;
    float lg[10];
    #pragma unroll
    for (int c = 0; c < 10; ++c) {
        float v = p0 * Wlin[l * 10 + c] + p1 * Wlin[(64 + l) * 10 + c];
        #pragma unroll
        for (int off = 32; off > 0; off >>= 1) v += __shfl_down(v, off);
        lg[c] = v;
    }
    if (l == 0) {
        float mx = -1e30f;
        #pragma unroll
        for (int c = 0; c < 10; ++c) { lg[c] += blin[c]; mx = fmaxf(mx, lg[c]); }
        float s = 0.f;
        #pragma unroll
        for (int c = 0; c < 10; ++c) s += expf(lg[c] - mx);
        float lse = mx + logf(s);
        #pragma unroll
        for (int c = 0; c < 10; ++c) out[g * 10 + c] = lg[c] - lse;
    }
}

extern "C" void kernel_launch(void* const* d_in, const int* in_sizes, int n_in,
                              void* d_out, int out_size, void* d_ws, size_t ws_size,
                              hipStream_t stream)
{
    const float* x    = (const float*)d_in[0];
    const int*   ei   = (const int*)d_in[1];
    const int*   batch= (const int*)d_in[2];
    const float* W1a  = (const float*)d_in[3];
    const float* b1a  = (const float*)d_in[4];
    const float* W1b  = (const float*)d_in[5];
    const float* b1b  = (const float*)d_in[6];
    const float* g1   = (const float*)d_in[7];
    const float* be1  = (const float*)d_in[8];
    const float* W2a  = (const float*)d_in[9];
    const float* b2a  = (const float*)d_in[10];
    const float* W2b  = (const float*)d_in[11];
    const float* b2b  = (const float*)d_in[12];
    const float* g2   = (const float*)d_in[13];
    const float* be2  = (const float*)d_in[14];
    const float* Wl   = (const float*)d_in[15];
    const float* bl   = (const float*)d_in[16];
    float* out = (float*)d_out;

    const int* src = ei;
    const int* dst = ei + N_EDGESC;

    const size_t NM = (size_t)N_NODES * HID;    // 12.8M
    char* wsb = (char*)d_ws;
    // bf16 activation buffers first (GEMM overreads up to 8KB past Ab/Bb tails
    // land in the following buffer — always valid memory)
    unsigned short* Ab  = (unsigned short*)wsb;                 // NM u16
    unsigned short* Bb  = Ab + NM;                              // NM u16
    unsigned short* Xb  = Bb + NM;                              // NM u16 (x, then h1, h2)
    float* C   = (float*)(Xb + NM);                             // NM f32 (pre-BN)
    float* S   = C + NM;                                        // 256
    float* SC  = S + 256;                                       // 256
    float* P   = SC + 256;                                      // 128*128
    unsigned short* WT1a = (unsigned short*)(P + (size_t)NGRAPH * HID); // 16384 u16 each
    unsigned short* WT1b = WT1a + 16384;
    unsigned short* WT2a = WT1b + 16384;
    unsigned short* WT2b = WT2a + 16384;
    int* deg    = (int*)(WT2b + 16384);
    int* off    = deg + N_NODES;
    int* cursor = off + N_NODES + 1;
    int* bsum   = cursor + N_NODES;
    int* eidx   = bsum + SCAN_BLOCKS;
    int* gstart = eidx + N_EDGESC;

    dim3 blk(256);
    const int edgeBlocks = (N_EDGESC + 255) / 256;     // 3125
    const int nodeBlocks = (N_NODES + 255) / 256;      // 391
    const int gemmBlocks = (N_NODES + 63) / 64;        // 1563
    const int ewBlocks = (N_NODES * 32) / 256;         // 12500
    const int aggBlocks = (N_NODES + 7) / 8;           // 12500
    const int cvtBlocks = (int)(NM / 4 + 255) / 256;   // 12500

    // ---- CSR build + conversions ----
    hipMemsetAsync(deg, 0, N_NODES * sizeof(int), stream);
    hipMemsetAsync(P, 0, (size_t)NGRAPH * HID * sizeof(float), stream);
    k_count<<<edgeBlocks, blk, 0, stream>>>(dst, deg);
    k_scan_block<<<SCAN_BLOCKS, blk, 0, stream>>>(deg, off, bsum);
    k_scan_top<<<1, 1, 0, stream>>>(bsum, off);
    k_scan_add<<<nodeBlocks, blk, 0, stream>>>(off, bsum, cursor);
    k_fill<<<edgeBlocks, blk, 0, stream>>>(src, dst, cursor, eidx);
    k_bounds<<<1, 128, 0, stream>>>(batch, gstart);
    k_cvt<<<cvtBlocks, blk, 0, stream>>>(x, Xb, (int)(NM / 4));
    k_wcvt<<<64, blk, 0, stream>>>(W1a, WT1a);
    k_wcvt<<<64, blk, 0, stream>>>(W1b, WT1b);
    k_wcvt<<<64, blk, 0, stream>>>(W2a, WT2a);
    k_wcvt<<<64, blk, 0, stream>>>(W2b, WT2b);

    // ---- conv1 ----
    k_aggregate<<<aggBlocks, blk, 0, stream>>>(Xb, off, eidx, Ab);
    k_gemm_mfma<<<gemmBlocks, blk, 0, stream>>>(Ab, WT1a, b1a, nullptr, Bb, N_NODES, 1);
    k_gemm_mfma<<<gemmBlocks, blk, 0, stream>>>(Bb, WT1b, b1b, C, nullptr, N_NODES, 0);
    hipMemsetAsync(S, 0, 256 * sizeof(float), stream);
    k_bnstats<<<256, blk, 0, stream>>>(C, S, N_NODES);
    k_bnfinalize<<<1, 128, 0, stream>>>(S, g1, be1, SC, N_NODES);
    k_bnapply<<<ewBlocks, blk, 0, stream>>>(C, SC, Xb, N_NODES);   // Xb = h1

    // ---- conv2 ----
    k_aggregate<<<aggBlocks, blk, 0, stream>>>(Xb, off, eidx, Ab);
    k_gemm_mfma<<<gemmBlocks, blk, 0, stream>>>(Ab, WT2a, b2a, nullptr, Bb, N_NODES, 1);
    k_gemm_mfma<<<gemmBlocks, blk, 0, stream>>>(Bb, WT2b, b2b, C, nullptr, N_NODES, 0);
    hipMemsetAsync(S, 0, 256 * sizeof(float), stream);
    k_bnstats<<<256, blk, 0, stream>>>(C, S, N_NODES);
    k_bnfinalize<<<1, 128, 0, stream>>>(S, g2, be2, SC, N_NODES);
    k_bnapply<<<ewBlocks, blk, 0, stream>>>(C, SC, Xb, N_NODES);   // Xb = h2

    // ---- pool + head ----
    k_pool<<<NGRAPH * 16, blk, 0, stream>>>(Xb, gstart, P);
    k_head<<<NGRAPH, 64, 0, stream>>>(P, gstart, Wl, bl, out);
}

// Round 4
// 534.722 us; speedup vs baseline: 7.1301x; 1.2436x over previous
//
#include <hip/hip_runtime.h>

#define N_NODES 100000
#define N_EDGESC 800000
#define HID 128
#define NGRAPH 128
#define BN_EPS 1e-5f
#define SCAN_BLOCKS ((N_NODES + 1023) / 1024)   // 98
#define NREP 32   // BN-stats atomic replicas

typedef __bf16 bf16x8 __attribute__((ext_vector_type(8)));
typedef float f32x4 __attribute__((ext_vector_type(4)));

__device__ inline unsigned short f2bf(float f) {     // RNE fp32 -> bf16
    unsigned int u = __float_as_uint(f);
    unsigned int r = u + 0x7FFFu + ((u >> 16) & 1u);
    return (unsigned short)(r >> 16);
}
__device__ inline float b2f(unsigned short u) {
    return __uint_as_float(((unsigned int)u) << 16);
}

// ================= CSR build =================
__global__ __launch_bounds__(256) void k_count(const int* __restrict__ dst,
                                               int* __restrict__ deg)
{
    int e = blockIdx.x * 256 + threadIdx.x;
    if (e < N_EDGESC) atomicAdd(&deg[dst[e]], 1);
}

__global__ __launch_bounds__(256) void k_scan_block(const int* __restrict__ deg,
    int* __restrict__ off, int* __restrict__ bsum)
{
    __shared__ int ts[256];
    int base = blockIdx.x * 1024 + threadIdx.x * 4;
    int v[4], s = 0;
    #pragma unroll
    for (int i = 0; i < 4; ++i) {
        int idx = base + i;
        v[i] = (idx < N_NODES) ? deg[idx] : 0;
        s += v[i];
    }
    ts[threadIdx.x] = s;
    __syncthreads();
    for (int d = 1; d < 256; d <<= 1) {
        int t = (threadIdx.x >= d) ? ts[threadIdx.x - d] : 0;
        __syncthreads();
        ts[threadIdx.x] += t;
        __syncthreads();
    }
    int run = ts[threadIdx.x] - s;
    #pragma unroll
    for (int i = 0; i < 4; ++i) {
        int idx = base + i;
        if (idx < N_NODES) off[idx] = run;
        run += v[i];
    }
    if (threadIdx.x == 255) bsum[blockIdx.x] = ts[255];
}

__global__ void k_scan_top(int* __restrict__ bsum, int* __restrict__ off)
{
    int run = 0;
    for (int i = 0; i < SCAN_BLOCKS; ++i) { int t = bsum[i]; bsum[i] = run; run += t; }
    off[N_NODES] = run;
}

__global__ __launch_bounds__(256) void k_scan_add(int* __restrict__ off,
    const int* __restrict__ bsum, int* __restrict__ cursor)
{
    int i = blockIdx.x * 256 + threadIdx.x;
    if (i < N_NODES) {
        int o = off[i] + bsum[i >> 10];
        off[i] = o;
        cursor[i] = o;
    }
}

__global__ __launch_bounds__(256) void k_fill(const int* __restrict__ src,
    const int* __restrict__ dst, int* __restrict__ cursor, int* __restrict__ eidx)
{
    int e = blockIdx.x * 256 + threadIdx.x;
    if (e < N_EDGESC) {
        int p = atomicAdd(&cursor[dst[e]], 1);
        eidx[p] = src[e];
    }
}

// ================ dtype conversion ================
__global__ __launch_bounds__(256) void k_cvt(const float* __restrict__ X,
    unsigned short* __restrict__ Y, int n4)
{
    int i = blockIdx.x * 256 + threadIdx.x;
    if (i < n4) {
        float4 v = ((const float4*)X)[i];
        ((ushort4*)Y)[i] = make_ushort4(f2bf(v.x), f2bf(v.y), f2bf(v.z), f2bf(v.w));
    }
}

// convert + transpose all four 128x128 weights: WT[n][k] = bf16(W[k][n])
__global__ __launch_bounds__(256) void k_wcvt4(const float* __restrict__ Wa,
    const float* __restrict__ Wb, const float* __restrict__ Wc,
    const float* __restrict__ Wd, unsigned short* __restrict__ WT)
{
    int idx = blockIdx.x * 256 + threadIdx.x;   // 256 blocks -> 65536
    int mat = idx >> 14, w = idx & 16383;
    int k = w >> 7, n = w & 127;
    const float* W = (mat == 0) ? Wa : (mat == 1) ? Wb : (mat == 2) ? Wc : Wd;
    WT[mat * 16384 + n * 128 + k] = f2bf(W[w]);
}

// ======== gather aggregation (bf16): OUT[n] = X[n] + sum_{j->n} X[j] ========
// 32-lane group per node, ushort4 (8B) per lane.
__global__ __launch_bounds__(256) void k_aggregate(const unsigned short* __restrict__ X,
    const int* __restrict__ off, const int* __restrict__ eidx,
    unsigned short* __restrict__ OUT)
{
    int n = blockIdx.x * 8 + (threadIdx.x >> 5);
    if (n >= N_NODES) return;
    int lane = threadIdx.x & 31;
    int beg = off[n], end = off[n + 1];
    ushort4 o = ((const ushort4*)(X + (size_t)n * HID))[lane];
    float ax = b2f(o.x), ay = b2f(o.y), az = b2f(o.z), aw = b2f(o.w);
    for (int k = beg; k < end; ++k) {
        int s = eidx[k];
        ushort4 v = ((const ushort4*)(X + (size_t)s * HID))[lane];
        ax += b2f(v.x); ay += b2f(v.y); az += b2f(v.z); aw += b2f(v.w);
    }
    ((ushort4*)(OUT + (size_t)n * HID))[lane] =
        make_ushort4(f2bf(ax), f2bf(ay), f2bf(az), f2bf(aw));
}

// same, but input is pre-BN: h = relu(x*sc+sh) applied to every gathered row
__global__ __launch_bounds__(256) void k_aggregate_bn(const unsigned short* __restrict__ X,
    const float* __restrict__ SC,
    const int* __restrict__ off, const int* __restrict__ eidx,
    unsigned short* __restrict__ OUT)
{
    int n = blockIdx.x * 8 + (threadIdx.x >> 5);
    if (n >= N_NODES) return;
    int lane = threadIdx.x & 31;
    float4 sc = ((const float4*)SC)[lane];
    float4 sh = ((const float4*)SC)[32 + lane];
    int beg = off[n], end = off[n + 1];
    ushort4 o = ((const ushort4*)(X + (size_t)n * HID))[lane];
    float ax = fmaxf(b2f(o.x) * sc.x + sh.x, 0.f);
    float ay = fmaxf(b2f(o.y) * sc.y + sh.y, 0.f);
    float az = fmaxf(b2f(o.z) * sc.z + sh.z, 0.f);
    float aw = fmaxf(b2f(o.w) * sc.w + sh.w, 0.f);
    for (int k = beg; k < end; ++k) {
        int s = eidx[k];
        ushort4 v = ((const ushort4*)(X + (size_t)s * HID))[lane];
        ax += fmaxf(b2f(v.x) * sc.x + sh.x, 0.f);
        ay += fmaxf(b2f(v.y) * sc.y + sh.y, 0.f);
        az += fmaxf(b2f(v.z) * sc.z + sh.z, 0.f);
        aw += fmaxf(b2f(v.w) * sc.w + sh.w, 0.f);
    }
    ((ushort4*)(OUT + (size_t)n * HID))[lane] =
        make_ushort4(f2bf(ax), f2bf(ay), f2bf(az), f2bf(aw));
}

// ============== MFMA GEMM: Cb[M,128] = act(A @ W + b), K=128, bf16 out ======
__global__ __launch_bounds__(256) void k_gemm_mfma(const unsigned short* __restrict__ A,
    const unsigned short* __restrict__ WT, const float* __restrict__ bias,
    unsigned short* __restrict__ Cb, int M, int relu)
{
    const int tid = threadIdx.x;
    const int wave = tid >> 6;
    const int lane = tid & 63;
    const int m = lane & 15;
    const int quad = lane >> 4;
    const int base = blockIdx.x * 64 + wave * 16;

    f32x4 acc[8];
    #pragma unroll
    for (int n0 = 0; n0 < 8; ++n0) acc[n0] = {0.f, 0.f, 0.f, 0.f};

    const unsigned short* arow = A + (size_t)(base + m) * HID + quad * 8;
    const unsigned short* wrow = WT + (size_t)m * HID + quad * 8;

    #pragma unroll
    for (int kk = 0; kk < 4; ++kk) {
        bf16x8 a = *(const bf16x8*)(arow + kk * 32);
        #pragma unroll
        for (int n0 = 0; n0 < 8; ++n0) {
            bf16x8 b = *(const bf16x8*)(wrow + (size_t)n0 * 16 * HID + kk * 32);
            acc[n0] = __builtin_amdgcn_mfma_f32_16x16x32_bf16(a, b, acc[n0], 0, 0, 0);
        }
    }

    #pragma unroll
    for (int n0 = 0; n0 < 8; ++n0) {
        float bv = bias[n0 * 16 + m];
        #pragma unroll
        for (int r = 0; r < 4; ++r) {
            int row = base + quad * 4 + r;
            if (row < M) {
                float v = acc[n0][r] + bv;
                if (relu) v = fmaxf(v, 0.f);
                Cb[(size_t)row * HID + n0 * 16 + m] = f2bf(v);
            }
        }
    }
}

// ---------------- BN stats: bf16 input, replica atomics ----------------
__global__ __launch_bounds__(256) void k_bnstats(const unsigned short* __restrict__ X,
    float* __restrict__ Srep, int M)
{
    int f = threadIdx.x & 127;
    int half = threadIdx.x >> 7;
    float s = 0.f, s2 = 0.f;
    for (int r = blockIdx.x * 2 + half; r < M; r += gridDim.x * 2) {
        float v = b2f(X[(size_t)r * HID + f]);
        s += v; s2 += v * v;
    }
    __shared__ float ls[512];
    ls[threadIdx.x] = s;
    ls[256 + threadIdx.x] = s2;
    __syncthreads();
    if (threadIdx.x < 128) {
        float* R = Srep + (size_t)(blockIdx.x & (NREP - 1)) * 256;
        atomicAdd(&R[threadIdx.x], ls[threadIdx.x] + ls[threadIdx.x + 128]);
        atomicAdd(&R[128 + threadIdx.x], ls[256 + threadIdx.x] + ls[384 + threadIdx.x]);
    }
}

__global__ void k_bnfinalize(const float* __restrict__ Srep,
    const float* __restrict__ gamma, const float* __restrict__ beta,
    float* __restrict__ SC, int M)
{
    int f = threadIdx.x;   // 128
    float s = 0.f, s2 = 0.f;
    for (int r = 0; r < NREP; ++r) {
        s += Srep[r * 256 + f];
        s2 += Srep[r * 256 + 128 + f];
    }
    float mean = s / (float)M;
    float var = s2 / (float)M - mean * mean;
    var = fmaxf(var, 0.f);
    float sc = gamma[f] * rsqrtf(var + BN_EPS);
    SC[f] = sc;
    SC[HID + f] = beta[f] - mean * sc;
}

// ---------------- pooling (fused BN+ReLU) ----------------
__global__ void k_bounds(const int* __restrict__ batch, int* __restrict__ gstart)
{
    int g = threadIdx.x;
    int lo = 0, hi = N_NODES;
    while (lo < hi) {
        int mid = (lo + hi) >> 1;
        if (batch[mid] < g) lo = mid + 1; else hi = mid;
    }
    gstart[g] = lo;
    if (g == 0) gstart[NGRAPH] = N_NODES;
}

__global__ __launch_bounds__(256) void k_pool(const unsigned short* __restrict__ H,
    const float* __restrict__ SC, const int* __restrict__ gstart,
    float* __restrict__ P)
{
    int g = blockIdx.x >> 4, part = blockIdx.x & 15;
    int beg = gstart[g], end = gstart[g + 1];
    int f = threadIdx.x & 127, half = threadIdx.x >> 7;
    float sc = SC[f], sh = SC[HID + f];
    float s = 0.f;
    for (int r = beg + part * 2 + half; r < end; r += 32)
        s += fmaxf(b2f(H[(size_t)r * HID + f]) * sc + sh, 0.f);
    __shared__ float ls[256];
    ls[threadIdx.x] = s;
    __syncthreads();
    if (threadIdx.x < 128)
        atomicAdd(&P[g * HID + threadIdx.x], ls[threadIdx.x] + ls[threadIdx.x + 128]);
}

// ---------------- classifier head + log_softmax ----------------
__global__ void k_head(const float* __restrict__ P, const int* __restrict__ gstart,
    const float* __restrict__ Wlin, const float* __restrict__ blin,
    float* __restrict__ out)
{
    int g = blockIdx.x;
    int l = threadIdx.x;    // 64 lanes
    float inv = 1.f / (float)max(gstart[g + 1] - gstart[g], 1);
    float p0 = P[(size_t)g * HID + l] * inv;
    float p1 = P[(size_t)g * HID + 64 + l] * inv;
    float lg[10];
    #pragma unroll
    for (int c = 0; c < 10; ++c) {
        float v = p0 * Wlin[l * 10 + c] + p1 * Wlin[(64 + l) * 10 + c];
        #pragma unroll
        for (int off = 32; off > 0; off >>= 1) v += __shfl_down(v, off);
        lg[c] = v;
    }
    if (l == 0) {
        float mx = -1e30f;
        #pragma unroll
        for (int c = 0; c < 10; ++c) { lg[c] += blin[c]; mx = fmaxf(mx, lg[c]); }
        float s = 0.f;
        #pragma unroll
        for (int c = 0; c < 10; ++c) s += expf(lg[c] - mx);
        float lse = mx + logf(s);
        #pragma unroll
        for (int c = 0; c < 10; ++c) out[g * 10 + c] = lg[c] - lse;
    }
}

extern "C" void kernel_launch(void* const* d_in, const int* in_sizes, int n_in,
                              void* d_out, int out_size, void* d_ws, size_t ws_size,
                              hipStream_t stream)
{
    const float* x    = (const float*)d_in[0];
    const int*   ei   = (const int*)d_in[1];
    const int*   batch= (const int*)d_in[2];
    const float* W1a  = (const float*)d_in[3];
    const float* b1a  = (const float*)d_in[4];
    const float* W1b  = (const float*)d_in[5];
    const float* b1b  = (const float*)d_in[6];
    const float* g1   = (const float*)d_in[7];
    const float* be1  = (const float*)d_in[8];
    const float* W2a  = (const float*)d_in[9];
    const float* b2a  = (const float*)d_in[10];
    const float* W2b  = (const float*)d_in[11];
    const float* b2b  = (const float*)d_in[12];
    const float* g2   = (const float*)d_in[13];
    const float* be2  = (const float*)d_in[14];
    const float* Wl   = (const float*)d_in[15];
    const float* bl   = (const float*)d_in[16];
    float* out = (float*)d_out;

    const int* src = ei;
    const int* dst = ei + N_EDGESC;

    const size_t NM = (size_t)N_NODES * HID;    // 12.8M
    char* wsb = (char*)d_ws;
    // bf16 buffers first; GEMM tail overreads (rows 100000..100031) land in
    // the next buffer — always valid memory.
    unsigned short* Ab  = (unsigned short*)wsb;                 // NM u16 (agg out)
    unsigned short* Bb  = Ab + NM;                              // NM u16 (hidden)
    unsigned short* Xb  = Bb + NM;                              // NM u16 (x / Cb1 / Cb2)
    float* Srep1 = (float*)(Xb + NM);                           // NREP*256
    float* Srep2 = Srep1 + NREP * 256;                          // NREP*256
    float* SC   = Srep2 + NREP * 256;                           // 256
    float* P    = SC + 256;                                     // 128*128
    unsigned short* WT = (unsigned short*)(P + (size_t)NGRAPH * HID); // 4*16384 u16
    int* deg    = (int*)(WT + 4 * 16384);
    int* off    = deg + N_NODES;
    int* cursor = off + N_NODES + 1;
    int* bsum   = cursor + N_NODES;
    int* eidx   = bsum + SCAN_BLOCKS;
    int* gstart = eidx + N_EDGESC;

    dim3 blk(256);
    const int edgeBlocks = (N_EDGESC + 255) / 256;     // 3125
    const int nodeBlocks = (N_NODES + 255) / 256;      // 391
    const int gemmBlocks = (N_NODES + 63) / 64;        // 1563
    const int aggBlocks = (N_NODES + 7) / 8;           // 12500
    const int cvtBlocks = (int)(NM / 4 + 255) / 256;   // 12500

    // ---- CSR build + conversions ----
    hipMemsetAsync(deg, 0, N_NODES * sizeof(int), stream);
    hipMemsetAsync(P, 0, (size_t)NGRAPH * HID * sizeof(float), stream);
    hipMemsetAsync(Srep1, 0, 2 * NREP * 256 * sizeof(float), stream);
    k_count<<<edgeBlocks, blk, 0, stream>>>(dst, deg);
    k_scan_block<<<SCAN_BLOCKS, blk, 0, stream>>>(deg, off, bsum);
    k_scan_top<<<1, 1, 0, stream>>>(bsum, off);
    k_scan_add<<<nodeBlocks, blk, 0, stream>>>(off, bsum, cursor);
    k_fill<<<edgeBlocks, blk, 0, stream>>>(src, dst, cursor, eidx);
    k_bounds<<<1, 128, 0, stream>>>(batch, gstart);
    k_cvt<<<cvtBlocks, blk, 0, stream>>>(x, Xb, (int)(NM / 4));
    k_wcvt4<<<256, blk, 0, stream>>>(W1a, W1b, W2a, W2b, WT);

    // ---- conv1 ----
    k_aggregate<<<aggBlocks, blk, 0, stream>>>(Xb, off, eidx, Ab);
    k_gemm_mfma<<<gemmBlocks, blk, 0, stream>>>(Ab, WT,          b1a, Bb, N_NODES, 1);
    k_gemm_mfma<<<gemmBlocks, blk, 0, stream>>>(Bb, WT + 16384,  b1b, Xb, N_NODES, 0); // Xb = Cb1
    k_bnstats<<<2048, blk, 0, stream>>>(Xb, Srep1, N_NODES);
    k_bnfinalize<<<1, 128, 0, stream>>>(Srep1, g1, be1, SC, N_NODES);

    // ---- conv2 (BN1+ReLU fused into the gather) ----
    k_aggregate_bn<<<aggBlocks, blk, 0, stream>>>(Xb, SC, off, eidx, Ab);
    k_gemm_mfma<<<gemmBlocks, blk, 0, stream>>>(Ab, WT + 2*16384, b2a, Bb, N_NODES, 1);
    k_gemm_mfma<<<gemmBlocks, blk, 0, stream>>>(Bb, WT + 3*16384, b2b, Xb, N_NODES, 0); // Xb = Cb2
    k_bnstats<<<2048, blk, 0, stream>>>(Xb, Srep2, N_NODES);
    k_bnfinalize<<<1, 128, 0, stream>>>(Srep2, g2, be2, SC, N_NODES);

    // ---- pool (BN2+ReLU fused) + head ----
    k_pool<<<NGRAPH * 16, blk, 0, stream>>>(Xb, SC, gstart, P);
    k_head<<<NGRAPH, 64, 0, stream>>>(P, gstart, Wl, bl, out);
}

// Round 5
// 487.196 us; speedup vs baseline: 7.8256x; 1.0975x over previous
//
#include <hip/hip_runtime.h>

#define N_NODES 100000
#define N_EDGESC 800000
#define HID 128
#define NGRAPH 128
#define BN_EPS 1e-5f
#define SCAN_BLOCKS ((N_NODES + 1023) / 1024)   // 98
#define NREP 32   // BN-stats atomic replicas
#define PS 136    // LDS row stride in shorts: 272B = 16B-aligned, bank-uniform

typedef __bf16 bf16x8 __attribute__((ext_vector_type(8)));
typedef float f32x4 __attribute__((ext_vector_type(4)));

__device__ inline unsigned short f2bf(float f) {     // RNE fp32 -> bf16
    unsigned int u = __float_as_uint(f);
    unsigned int r = u + 0x7FFFu + ((u >> 16) & 1u);
    return (unsigned short)(r >> 16);
}
__device__ inline float b2f(unsigned short u) {
    return __uint_as_float(((unsigned int)u) << 16);
}

// ================= CSR build =================
__global__ __launch_bounds__(256) void k_count(const int* __restrict__ dst,
                                               int* __restrict__ deg)
{
    int e = blockIdx.x * 256 + threadIdx.x;
    if (e < N_EDGESC) atomicAdd(&deg[dst[e]], 1);
}

__global__ __launch_bounds__(256) void k_scan_block(const int* __restrict__ deg,
    int* __restrict__ off, int* __restrict__ bsum)
{
    __shared__ int ts[256];
    int base = blockIdx.x * 1024 + threadIdx.x * 4;
    int v[4], s = 0;
    #pragma unroll
    for (int i = 0; i < 4; ++i) {
        int idx = base + i;
        v[i] = (idx < N_NODES) ? deg[idx] : 0;
        s += v[i];
    }
    ts[threadIdx.x] = s;
    __syncthreads();
    for (int d = 1; d < 256; d <<= 1) {
        int t = (threadIdx.x >= d) ? ts[threadIdx.x - d] : 0;
        __syncthreads();
        ts[threadIdx.x] += t;
        __syncthreads();
    }
    int run = ts[threadIdx.x] - s;
    #pragma unroll
    for (int i = 0; i < 4; ++i) {
        int idx = base + i;
        if (idx < N_NODES) off[idx] = run;
        run += v[i];
    }
    if (threadIdx.x == 255) bsum[blockIdx.x] = ts[255];
}

__global__ void k_scan_top(int* __restrict__ bsum, int* __restrict__ off)
{
    int run = 0;
    for (int i = 0; i < SCAN_BLOCKS; ++i) { int t = bsum[i]; bsum[i] = run; run += t; }
    off[N_NODES] = run;
}

__global__ __launch_bounds__(256) void k_scan_add(int* __restrict__ off,
    const int* __restrict__ bsum, int* __restrict__ cursor)
{
    int i = blockIdx.x * 256 + threadIdx.x;
    if (i < N_NODES) {
        int o = off[i] + bsum[i >> 10];
        off[i] = o;
        cursor[i] = o;
    }
}

__global__ __launch_bounds__(256) void k_fill(const int* __restrict__ src,
    const int* __restrict__ dst, int* __restrict__ cursor, int* __restrict__ eidx)
{
    int e = blockIdx.x * 256 + threadIdx.x;
    if (e < N_EDGESC) {
        int p = atomicAdd(&cursor[dst[e]], 1);
        eidx[p] = src[e];
    }
}

// ================ dtype conversion ================
__global__ __launch_bounds__(256) void k_cvt(const float* __restrict__ X,
    unsigned short* __restrict__ Y, int n4)
{
    int i = blockIdx.x * 256 + threadIdx.x;
    if (i < n4) {
        float4 v = ((const float4*)X)[i];
        ((ushort4*)Y)[i] = make_ushort4(f2bf(v.x), f2bf(v.y), f2bf(v.z), f2bf(v.w));
    }
}

__global__ __launch_bounds__(256) void k_wcvt4(const float* __restrict__ Wa,
    const float* __restrict__ Wb, const float* __restrict__ Wc,
    const float* __restrict__ Wd, unsigned short* __restrict__ WT)
{
    int idx = blockIdx.x * 256 + threadIdx.x;   // 256 blocks -> 65536
    int mat = idx >> 14, w = idx & 16383;
    int k = w >> 7, n = w & 127;
    const float* W = (mat == 0) ? Wa : (mat == 1) ? Wb : (mat == 2) ? Wc : Wd;
    WT[mat * 16384 + n * 128 + k] = f2bf(W[w]);
}

// ============== fused GIN conv layer ==============
// Per block: 64 nodes (16/wave, wave-private LDS region).
// Phase 1: gather rows (optionally BN+ReLU transformed) -> LDS bf16.
// Phase 2: GEMM-a (relu) via MFMA, hidden -> LDS, GEMM-b, store bf16 +
//          per-feature BN partial sums into replica accumulators.
template<bool BN>
__global__ __launch_bounds__(256) void k_conv(
    const unsigned short* __restrict__ X, const float* __restrict__ SC,
    const int* __restrict__ off, const int* __restrict__ eidx,
    const unsigned short* __restrict__ WTa, const float* __restrict__ ba,
    const unsigned short* __restrict__ WTb, const float* __restrict__ bb,
    unsigned short* __restrict__ Cb, float* __restrict__ Srep, int M)
{
    __shared__ unsigned short Hs[4][16 * PS];

    const int tid = threadIdx.x;
    const int wave = tid >> 6;
    const int lane = tid & 63;
    const int grp = (tid >> 5) & 1;    // half-wave group
    const int c = tid & 31;            // ushort4 chunk within row
    const int base = blockIdx.x * 64 + wave * 16;
    unsigned short* lds = Hs[wave];

    float4 sc, sh;
    if (BN) {
        sc = ((const float4*)SC)[c];
        sh = ((const float4*)SC)[32 + c];
    }

    // ---- Phase 1: gather ----
    for (int i = 0; i < 8; ++i) {
        int local = i * 2 + grp;
        int n = base + local;
        float ax = 0.f, ay = 0.f, az = 0.f, aw = 0.f;
        if (n < M) {
            ushort4 o = ((const ushort4*)(X + (size_t)n * HID))[c];
            if (BN) {
                ax = fmaxf(b2f(o.x) * sc.x + sh.x, 0.f);
                ay = fmaxf(b2f(o.y) * sc.y + sh.y, 0.f);
                az = fmaxf(b2f(o.z) * sc.z + sh.z, 0.f);
                aw = fmaxf(b2f(o.w) * sc.w + sh.w, 0.f);
            } else {
                ax = b2f(o.x); ay = b2f(o.y); az = b2f(o.z); aw = b2f(o.w);
            }
            int k = off[n], kend = off[n + 1];
            for (; k + 3 < kend; k += 4) {     // 4-way ILP batch
                int s0 = eidx[k], s1 = eidx[k + 1], s2 = eidx[k + 2], s3 = eidx[k + 3];
                ushort4 v0 = ((const ushort4*)(X + (size_t)s0 * HID))[c];
                ushort4 v1 = ((const ushort4*)(X + (size_t)s1 * HID))[c];
                ushort4 v2 = ((const ushort4*)(X + (size_t)s2 * HID))[c];
                ushort4 v3 = ((const ushort4*)(X + (size_t)s3 * HID))[c];
                if (BN) {
                    ax += fmaxf(b2f(v0.x)*sc.x+sh.x,0.f) + fmaxf(b2f(v1.x)*sc.x+sh.x,0.f)
                        + fmaxf(b2f(v2.x)*sc.x+sh.x,0.f) + fmaxf(b2f(v3.x)*sc.x+sh.x,0.f);
                    ay += fmaxf(b2f(v0.y)*sc.y+sh.y,0.f) + fmaxf(b2f(v1.y)*sc.y+sh.y,0.f)
                        + fmaxf(b2f(v2.y)*sc.y+sh.y,0.f) + fmaxf(b2f(v3.y)*sc.y+sh.y,0.f);
                    az += fmaxf(b2f(v0.z)*sc.z+sh.z,0.f) + fmaxf(b2f(v1.z)*sc.z+sh.z,0.f)
                        + fmaxf(b2f(v2.z)*sc.z+sh.z,0.f) + fmaxf(b2f(v3.z)*sc.z+sh.z,0.f);
                    aw += fmaxf(b2f(v0.w)*sc.w+sh.w,0.f) + fmaxf(b2f(v1.w)*sc.w+sh.w,0.f)
                        + fmaxf(b2f(v2.w)*sc.w+sh.w,0.f) + fmaxf(b2f(v3.w)*sc.w+sh.w,0.f);
                } else {
                    ax += b2f(v0.x) + b2f(v1.x) + b2f(v2.x) + b2f(v3.x);
                    ay += b2f(v0.y) + b2f(v1.y) + b2f(v2.y) + b2f(v3.y);
                    az += b2f(v0.z) + b2f(v1.z) + b2f(v2.z) + b2f(v3.z);
                    aw += b2f(v0.w) + b2f(v1.w) + b2f(v2.w) + b2f(v3.w);
                }
            }
            for (; k < kend; ++k) {
                int s0 = eidx[k];
                ushort4 v = ((const ushort4*)(X + (size_t)s0 * HID))[c];
                if (BN) {
                    ax += fmaxf(b2f(v.x)*sc.x+sh.x, 0.f);
                    ay += fmaxf(b2f(v.y)*sc.y+sh.y, 0.f);
                    az += fmaxf(b2f(v.z)*sc.z+sh.z, 0.f);
                    aw += fmaxf(b2f(v.w)*sc.w+sh.w, 0.f);
                } else {
                    ax += b2f(v.x); ay += b2f(v.y); az += b2f(v.z); aw += b2f(v.w);
                }
            }
        }
        unsigned int p0 = ((unsigned int)f2bf(ay) << 16) | f2bf(ax);
        unsigned int p1 = ((unsigned int)f2bf(aw) << 16) | f2bf(az);
        *(uint2*)(lds + local * PS + c * 4) = make_uint2(p0, p1);
    }
    __syncthreads();

    // ---- Phase 2: GEMM-a ----
    const int m = lane & 15;
    const int quad = lane >> 4;

    bf16x8 afr[4];
    #pragma unroll
    for (int kk = 0; kk < 4; ++kk)
        afr[kk] = *(const bf16x8*)(lds + m * PS + quad * 8 + kk * 32);

    f32x4 acc[8];
    #pragma unroll
    for (int n0 = 0; n0 < 8; ++n0) acc[n0] = {0.f, 0.f, 0.f, 0.f};

    #pragma unroll
    for (int kk = 0; kk < 4; ++kk) {
        #pragma unroll
        for (int n0 = 0; n0 < 8; ++n0) {
            bf16x8 b = *(const bf16x8*)(WTa + (size_t)(n0 * 16 + m) * HID + quad * 8 + kk * 32);
            acc[n0] = __builtin_amdgcn_mfma_f32_16x16x32_bf16(afr[kk], b, acc[n0], 0, 0, 0);
        }
    }

    // hidden = relu(acc + bias) -> LDS (wave-private region, reuse)
    __syncthreads();
    #pragma unroll
    for (int n0 = 0; n0 < 8; ++n0) {
        float bv = ba[n0 * 16 + m];
        #pragma unroll
        for (int r = 0; r < 4; ++r)
            lds[(quad * 4 + r) * PS + n0 * 16 + m] = f2bf(fmaxf(acc[n0][r] + bv, 0.f));
    }
    __syncthreads();

    // ---- GEMM-b ----
    bf16x8 hfr[4];
    #pragma unroll
    for (int kk = 0; kk < 4; ++kk)
        hfr[kk] = *(const bf16x8*)(lds + m * PS + quad * 8 + kk * 32);

    #pragma unroll
    for (int n0 = 0; n0 < 8; ++n0) acc[n0] = {0.f, 0.f, 0.f, 0.f};

    #pragma unroll
    for (int kk = 0; kk < 4; ++kk) {
        #pragma unroll
        for (int n0 = 0; n0 < 8; ++n0) {
            bf16x8 b = *(const bf16x8*)(WTb + (size_t)(n0 * 16 + m) * HID + quad * 8 + kk * 32);
            acc[n0] = __builtin_amdgcn_mfma_f32_16x16x32_bf16(hfr[kk], b, acc[n0], 0, 0, 0);
        }
    }

    // ---- epilogue: store + BN partial stats ----
    float s[8], s2[8];
    #pragma unroll
    for (int n0 = 0; n0 < 8; ++n0) {
        float bv = bb[n0 * 16 + m];
        float ls = 0.f, ls2 = 0.f;
        #pragma unroll
        for (int r = 0; r < 4; ++r) {
            int row = base + quad * 4 + r;
            if (row < M) {
                float v = acc[n0][r] + bv;
                Cb[(size_t)row * HID + n0 * 16 + m] = f2bf(v);
                ls += v; ls2 += v * v;
            }
        }
        s[n0] = ls; s2[n0] = ls2;
    }
    #pragma unroll
    for (int n0 = 0; n0 < 8; ++n0) {
        s[n0]  += __shfl_xor(s[n0], 16, 64);
        s[n0]  += __shfl_xor(s[n0], 32, 64);
        s2[n0] += __shfl_xor(s2[n0], 16, 64);
        s2[n0] += __shfl_xor(s2[n0], 32, 64);
    }
    if (quad == 0) {
        float* R = Srep + (size_t)((blockIdx.x * 4 + wave) & (NREP - 1)) * 256;
        #pragma unroll
        for (int n0 = 0; n0 < 8; ++n0) {
            atomicAdd(&R[n0 * 16 + m], s[n0]);
            atomicAdd(&R[128 + n0 * 16 + m], s2[n0]);
        }
    }
}

__global__ void k_bnfinalize(const float* __restrict__ Srep,
    const float* __restrict__ gamma, const float* __restrict__ beta,
    float* __restrict__ SC, int M)
{
    int f = threadIdx.x;   // 128
    float s = 0.f, s2 = 0.f;
    for (int r = 0; r < NREP; ++r) {
        s += Srep[r * 256 + f];
        s2 += Srep[r * 256 + 128 + f];
    }
    float mean = s / (float)M;
    float var = s2 / (float)M - mean * mean;
    var = fmaxf(var, 0.f);
    float sc = gamma[f] * rsqrtf(var + BN_EPS);
    SC[f] = sc;
    SC[HID + f] = beta[f] - mean * sc;
}

// ---------------- pooling (fused BN+ReLU) ----------------
__global__ void k_bounds(const int* __restrict__ batch, int* __restrict__ gstart)
{
    int g = threadIdx.x;
    int lo = 0, hi = N_NODES;
    while (lo < hi) {
        int mid = (lo + hi) >> 1;
        if (batch[mid] < g) lo = mid + 1; else hi = mid;
    }
    gstart[g] = lo;
    if (g == 0) gstart[NGRAPH] = N_NODES;
}

__global__ __launch_bounds__(256) void k_pool(const unsigned short* __restrict__ H,
    const float* __restrict__ SC, const int* __restrict__ gstart,
    float* __restrict__ P)
{
    int g = blockIdx.x >> 4, part = blockIdx.x & 15;
    int beg = gstart[g], end = gstart[g + 1];
    int f = threadIdx.x & 127, half = threadIdx.x >> 7;
    float sc = SC[f], sh = SC[HID + f];
    float s = 0.f;
    for (int r = beg + part * 2 + half; r < end; r += 32)
        s += fmaxf(b2f(H[(size_t)r * HID + f]) * sc + sh, 0.f);
    __shared__ float ls[256];
    ls[threadIdx.x] = s;
    __syncthreads();
    if (threadIdx.x < 128)
        atomicAdd(&P[g * HID + threadIdx.x], ls[threadIdx.x] + ls[threadIdx.x + 128]);
}

// ---------------- classifier head + log_softmax ----------------
__global__ void k_head(const float* __restrict__ P, const int* __restrict__ gstart,
    const float* __restrict__ Wlin, const float* __restrict__ blin,
    float* __restrict__ out)
{
    int g = blockIdx.x;
    int l = threadIdx.x;    // 64 lanes
    float inv = 1.f / (float)max(gstart[g + 1] - gstart[g], 1);
    float p0 = P[(size_t)g * HID + l] * inv;
    float p1 = P[(size_t)g * HID + 64 + l] * inv;
    float lg[10];
    #pragma unroll
    for (int c = 0; c < 10; ++c) {
        float v = p0 * Wlin[l * 10 + c] + p1 * Wlin[(64 + l) * 10 + c];
        #pragma unroll
        for (int off = 32; off > 0; off >>= 1) v += __shfl_down(v, off);
        lg[c] = v;
    }
    if (l == 0) {
        float mx = -1e30f;
        #pragma unroll
        for (int c = 0; c < 10; ++c) { lg[c] += blin[c]; mx = fmaxf(mx, lg[c]); }
        float s = 0.f;
        #pragma unroll
        for (int c = 0; c < 10; ++c) s += expf(lg[c] - mx);
        float lse = mx + logf(s);
        #pragma unroll
        for (int c = 0; c < 10; ++c) out[g * 10 + c] = lg[c] - lse;
    }
}

extern "C" void kernel_launch(void* const* d_in, const int* in_sizes, int n_in,
                              void* d_out, int out_size, void* d_ws, size_t ws_size,
                              hipStream_t stream)
{
    const float* x    = (const float*)d_in[0];
    const int*   ei   = (const int*)d_in[1];
    const int*   batch= (const int*)d_in[2];
    const float* W1a  = (const float*)d_in[3];
    const float* b1a  = (const float*)d_in[4];
    const float* W1b  = (const float*)d_in[5];
    const float* b1b  = (const float*)d_in[6];
    const float* g1   = (const float*)d_in[7];
    const float* be1  = (const float*)d_in[8];
    const float* W2a  = (const float*)d_in[9];
    const float* b2a  = (const float*)d_in[10];
    const float* W2b  = (const float*)d_in[11];
    const float* b2b  = (const float*)d_in[12];
    const float* g2   = (const float*)d_in[13];
    const float* be2  = (const float*)d_in[14];
    const float* Wl   = (const float*)d_in[15];
    const float* bl   = (const float*)d_in[16];
    float* out = (float*)d_out;

    const int* src = ei;
    const int* dst = ei + N_EDGESC;

    const size_t NM = (size_t)N_NODES * HID;    // 12.8M
    char* wsb = (char*)d_ws;
    unsigned short* Xb  = (unsigned short*)wsb;                 // NM u16 (x / Cb2)
    unsigned short* Yb  = Xb + NM;                              // NM u16 (Cb1)
    float* Srep1 = (float*)(Yb + NM);                           // NREP*256
    float* Srep2 = Srep1 + NREP * 256;                          // NREP*256
    float* SC1  = Srep2 + NREP * 256;                           // 256
    float* SC2  = SC1 + 256;                                    // 256
    float* P    = SC2 + 256;                                    // 128*128
    unsigned short* WT = (unsigned short*)(P + (size_t)NGRAPH * HID); // 4*16384 u16
    int* deg    = (int*)(WT + 4 * 16384);
    int* off    = deg + N_NODES;
    int* cursor = off + N_NODES + 1;
    int* bsum   = cursor + N_NODES;
    int* eidx   = bsum + SCAN_BLOCKS;
    int* gstart = eidx + N_EDGESC;

    dim3 blk(256);
    const int edgeBlocks = (N_EDGESC + 255) / 256;     // 3125
    const int nodeBlocks = (N_NODES + 255) / 256;      // 391
    const int convBlocks = (N_NODES + 63) / 64;        // 1563
    const int cvtBlocks = (int)(NM / 4 + 255) / 256;   // 12500

    // ---- CSR build + conversions ----
    hipMemsetAsync(deg, 0, N_NODES * sizeof(int), stream);
    hipMemsetAsync(P, 0, (size_t)NGRAPH * HID * sizeof(float), stream);
    hipMemsetAsync(Srep1, 0, 2 * NREP * 256 * sizeof(float), stream);
    k_count<<<edgeBlocks, blk, 0, stream>>>(dst, deg);
    k_scan_block<<<SCAN_BLOCKS, blk, 0, stream>>>(deg, off, bsum);
    k_scan_top<<<1, 1, 0, stream>>>(bsum, off);
    k_scan_add<<<nodeBlocks, blk, 0, stream>>>(off, bsum, cursor);
    k_fill<<<edgeBlocks, blk, 0, stream>>>(src, dst, cursor, eidx);
    k_bounds<<<1, 128, 0, stream>>>(batch, gstart);
    k_cvt<<<cvtBlocks, blk, 0, stream>>>(x, Xb, (int)(NM / 4));
    k_wcvt4<<<256, blk, 0, stream>>>(W1a, W1b, W2a, W2b, WT);

    // ---- conv1 (fused gather + MLP + BN stats) ----
    k_conv<false><<<convBlocks, blk, 0, stream>>>(Xb, nullptr, off, eidx,
        WT, b1a, WT + 16384, b1b, Yb, Srep1, N_NODES);
    k_bnfinalize<<<1, 128, 0, stream>>>(Srep1, g1, be1, SC1, N_NODES);

    // ---- conv2 (BN1+ReLU fused into gather) ----
    k_conv<true><<<convBlocks, blk, 0, stream>>>(Yb, SC1, off, eidx,
        WT + 2 * 16384, b2a, WT + 3 * 16384, b2b, Xb, Srep2, N_NODES);
    k_bnfinalize<<<1, 128, 0, stream>>>(Srep2, g2, be2, SC2, N_NODES);

    // ---- pool (BN2+ReLU fused) + head ----
    k_pool<<<NGRAPH * 16, blk, 0, stream>>>(Xb, SC2, gstart, P);
    k_head<<<NGRAPH, 64, 0, stream>>>(P, gstart, Wl, bl, out);
}

// Round 6
// 446.478 us; speedup vs baseline: 8.5393x; 1.0912x over previous
//
#include <hip/hip_runtime.h>

#define N_NODES 100000
#define N_EDGESC 800000
#define HID 128
#define NGRAPH 128
#define BN_EPS 1e-5f
#define SCAN_BLOCKS ((N_NODES + 1023) / 1024)   // 98
#define NREP 32   // BN-stats atomic replicas
#define PS 136    // LDS row stride in shorts: 272B = 16B-aligned

typedef __bf16 bf16x8 __attribute__((ext_vector_type(8)));
typedef float f32x4 __attribute__((ext_vector_type(4)));

__device__ inline unsigned short f2bf(float f) {     // RNE fp32 -> bf16
    unsigned int u = __float_as_uint(f);
    unsigned int r = u + 0x7FFFu + ((u >> 16) & 1u);
    return (unsigned short)(r >> 16);
}
__device__ inline float b2f(unsigned short u) {
    return __uint_as_float(((unsigned int)u) << 16);
}

// ================= CSR build =================
__global__ __launch_bounds__(256) void k_count(const int* __restrict__ dst,
                                               int* __restrict__ deg)
{
    int e = blockIdx.x * 256 + threadIdx.x;
    if (e < N_EDGESC) atomicAdd(&deg[dst[e]], 1);
}

__global__ __launch_bounds__(256) void k_scan_block(const int* __restrict__ deg,
    int* __restrict__ off, int* __restrict__ bsum)
{
    __shared__ int ts[256];
    int base = blockIdx.x * 1024 + threadIdx.x * 4;
    int v[4], s = 0;
    #pragma unroll
    for (int i = 0; i < 4; ++i) {
        int idx = base + i;
        v[i] = (idx < N_NODES) ? deg[idx] : 0;
        s += v[i];
    }
    ts[threadIdx.x] = s;
    __syncthreads();
    for (int d = 1; d < 256; d <<= 1) {
        int t = (threadIdx.x >= d) ? ts[threadIdx.x - d] : 0;
        __syncthreads();
        ts[threadIdx.x] += t;
        __syncthreads();
    }
    int run = ts[threadIdx.x] - s;
    #pragma unroll
    for (int i = 0; i < 4; ++i) {
        int idx = base + i;
        if (idx < N_NODES) off[idx] = run;
        run += v[i];
    }
    if (threadIdx.x == 255) bsum[blockIdx.x] = ts[255];
}

__global__ void k_scan_top(int* __restrict__ bsum, int* __restrict__ off)
{
    int run = 0;
    for (int i = 0; i < SCAN_BLOCKS; ++i) { int t = bsum[i]; bsum[i] = run; run += t; }
    off[N_NODES] = run;
}

__global__ __launch_bounds__(256) void k_scan_add(int* __restrict__ off,
    const int* __restrict__ bsum, int* __restrict__ cursor)
{
    int i = blockIdx.x * 256 + threadIdx.x;
    if (i < N_NODES) {
        int o = off[i] + bsum[i >> 10];
        off[i] = o;
        cursor[i] = o;
    }
}

__global__ __launch_bounds__(256) void k_fill(const int* __restrict__ src,
    const int* __restrict__ dst, int* __restrict__ cursor, int* __restrict__ eidx)
{
    int e = blockIdx.x * 256 + threadIdx.x;
    if (e < N_EDGESC) {
        int p = atomicAdd(&cursor[dst[e]], 1);
        eidx[p] = src[e];
    }
}

// ================ dtype conversion ================
__global__ __launch_bounds__(256) void k_cvt(const float* __restrict__ X,
    unsigned short* __restrict__ Y, int n4)
{
    int i = blockIdx.x * 256 + threadIdx.x;
    if (i < n4) {
        float4 v = ((const float4*)X)[i];
        ((ushort4*)Y)[i] = make_ushort4(f2bf(v.x), f2bf(v.y), f2bf(v.z), f2bf(v.w));
    }
}

__global__ __launch_bounds__(256) void k_wcvt4(const float* __restrict__ Wa,
    const float* __restrict__ Wb, const float* __restrict__ Wc,
    const float* __restrict__ Wd, unsigned short* __restrict__ WT)
{
    int idx = blockIdx.x * 256 + threadIdx.x;   // 256 blocks -> 65536
    int mat = idx >> 14, w = idx & 16383;
    int k = w >> 7, n = w & 127;
    const float* W = (mat == 0) ? Wa : (mat == 1) ? Wb : (mat == 2) ? Wc : Wd;
    WT[mat * 16384 + n * 128 + k] = f2bf(W[w]);
}

// ================ gather: OUT[n] = f(X[n]) + sum f(X[j]) ================
// 16 lanes per node, uint4 = 8 bf16 (16B) per lane; 16 nodes/block.
// 4-way edge ILP -> 64B outstanding per lane.
template<bool BN>
__device__ inline void acc_row(float* acc, uint4 v,
                               const float* sc, const float* sh)
{
    unsigned int u[4] = {v.x, v.y, v.z, v.w};
    #pragma unroll
    for (int j = 0; j < 4; ++j) {
        float lo = b2f((unsigned short)u[j]);
        float hi = b2f((unsigned short)(u[j] >> 16));
        if (BN) {
            lo = fmaxf(lo * sc[2*j]   + sh[2*j],   0.f);
            hi = fmaxf(hi * sc[2*j+1] + sh[2*j+1], 0.f);
        }
        acc[2*j]   += lo;
        acc[2*j+1] += hi;
    }
}

template<bool BN>
__global__ __launch_bounds__(256) void k_gather(
    const unsigned short* __restrict__ X, const float* __restrict__ SC,
    const int* __restrict__ off, const int* __restrict__ eidx,
    unsigned short* __restrict__ OUT, int M)
{
    int n = blockIdx.x * 16 + (threadIdx.x >> 4);
    if (n >= M) return;
    const int lane = threadIdx.x & 15;
    const size_t co = (size_t)lane * 8;

    float sc[8], sh[8];
    if (BN) {
        *(float4*)&sc[0] = ((const float4*)SC)[lane * 2];
        *(float4*)&sc[4] = ((const float4*)SC)[lane * 2 + 1];
        *(float4*)&sh[0] = ((const float4*)SC)[32 + lane * 2];
        *(float4*)&sh[4] = ((const float4*)SC)[32 + lane * 2 + 1];
    }

    float acc[8] = {0.f, 0.f, 0.f, 0.f, 0.f, 0.f, 0.f, 0.f};
    acc_row<BN>(acc, *(const uint4*)(X + (size_t)n * HID + co), sc, sh);

    int k = off[n], kend = off[n + 1];
    for (; k + 3 < kend; k += 4) {
        int s0 = eidx[k], s1 = eidx[k+1], s2 = eidx[k+2], s3 = eidx[k+3];
        uint4 v0 = *(const uint4*)(X + (size_t)s0 * HID + co);
        uint4 v1 = *(const uint4*)(X + (size_t)s1 * HID + co);
        uint4 v2 = *(const uint4*)(X + (size_t)s2 * HID + co);
        uint4 v3 = *(const uint4*)(X + (size_t)s3 * HID + co);
        acc_row<BN>(acc, v0, sc, sh);
        acc_row<BN>(acc, v1, sc, sh);
        acc_row<BN>(acc, v2, sc, sh);
        acc_row<BN>(acc, v3, sc, sh);
    }
    for (; k < kend; ++k) {
        uint4 v = *(const uint4*)(X + (size_t)eidx[k] * HID + co);
        acc_row<BN>(acc, v, sc, sh);
    }

    uint4 o;
    o.x = (unsigned int)f2bf(acc[0]) | ((unsigned int)f2bf(acc[1]) << 16);
    o.y = (unsigned int)f2bf(acc[2]) | ((unsigned int)f2bf(acc[3]) << 16);
    o.z = (unsigned int)f2bf(acc[4]) | ((unsigned int)f2bf(acc[5]) << 16);
    o.w = (unsigned int)f2bf(acc[6]) | ((unsigned int)f2bf(acc[7]) << 16);
    *(uint4*)(OUT + (size_t)n * HID + co) = o;
}

// ============== fused MLP: Cb = (A@Wa+ba).relu() @ Wb + bb, + BN stats ======
// Block = 4 waves x 16 rows; A-frags from global, hidden via wave-private LDS.
__global__ __launch_bounds__(256) void k_mlp(
    const unsigned short* __restrict__ A,
    const unsigned short* __restrict__ WTa, const float* __restrict__ ba,
    const unsigned short* __restrict__ WTb, const float* __restrict__ bb,
    unsigned short* __restrict__ Cb, float* __restrict__ Srep, int M)
{
    __shared__ unsigned short Hs[4][16 * PS];

    const int tid = threadIdx.x;
    const int wave = tid >> 6;
    const int lane = tid & 63;
    const int m = lane & 15;
    const int quad = lane >> 4;
    const int base = blockIdx.x * 64 + wave * 16;
    unsigned short* lds = Hs[wave];

    // ---- GEMM-a (A rows direct from global; tail rows overread valid mem) ----
    const unsigned short* arow = A + (size_t)(base + m) * HID + quad * 8;
    f32x4 acc[8];
    #pragma unroll
    for (int n0 = 0; n0 < 8; ++n0) acc[n0] = {0.f, 0.f, 0.f, 0.f};

    #pragma unroll
    for (int kk = 0; kk < 4; ++kk) {
        bf16x8 a = *(const bf16x8*)(arow + kk * 32);
        #pragma unroll
        for (int n0 = 0; n0 < 8; ++n0) {
            bf16x8 b = *(const bf16x8*)(WTa + (size_t)(n0 * 16 + m) * HID + quad * 8 + kk * 32);
            acc[n0] = __builtin_amdgcn_mfma_f32_16x16x32_bf16(a, b, acc[n0], 0, 0, 0);
        }
    }

    // hidden = relu(acc + bias) -> LDS (wave-private region)
    #pragma unroll
    for (int n0 = 0; n0 < 8; ++n0) {
        float bv = ba[n0 * 16 + m];
        #pragma unroll
        for (int r = 0; r < 4; ++r)
            lds[(quad * 4 + r) * PS + n0 * 16 + m] = f2bf(fmaxf(acc[n0][r] + bv, 0.f));
    }
    __syncthreads();

    // ---- GEMM-b ----
    bf16x8 hfr[4];
    #pragma unroll
    for (int kk = 0; kk < 4; ++kk)
        hfr[kk] = *(const bf16x8*)(lds + m * PS + quad * 8 + kk * 32);

    #pragma unroll
    for (int n0 = 0; n0 < 8; ++n0) acc[n0] = {0.f, 0.f, 0.f, 0.f};

    #pragma unroll
    for (int kk = 0; kk < 4; ++kk) {
        #pragma unroll
        for (int n0 = 0; n0 < 8; ++n0) {
            bf16x8 b = *(const bf16x8*)(WTb + (size_t)(n0 * 16 + m) * HID + quad * 8 + kk * 32);
            acc[n0] = __builtin_amdgcn_mfma_f32_16x16x32_bf16(hfr[kk], b, acc[n0], 0, 0, 0);
        }
    }

    // ---- epilogue: store bf16 + BN partial stats ----
    float s[8], s2[8];
    #pragma unroll
    for (int n0 = 0; n0 < 8; ++n0) {
        float bv = bb[n0 * 16 + m];
        float ls = 0.f, ls2 = 0.f;
        #pragma unroll
        for (int r = 0; r < 4; ++r) {
            int row = base + quad * 4 + r;
            if (row < M) {
                float v = acc[n0][r] + bv;
                Cb[(size_t)row * HID + n0 * 16 + m] = f2bf(v);
                ls += v; ls2 += v * v;
            }
        }
        s[n0] = ls; s2[n0] = ls2;
    }
    #pragma unroll
    for (int n0 = 0; n0 < 8; ++n0) {
        s[n0]  += __shfl_xor(s[n0], 16, 64);
        s[n0]  += __shfl_xor(s[n0], 32, 64);
        s2[n0] += __shfl_xor(s2[n0], 16, 64);
        s2[n0] += __shfl_xor(s2[n0], 32, 64);
    }
    if (quad == 0) {
        float* R = Srep + (size_t)((blockIdx.x * 4 + wave) & (NREP - 1)) * 256;
        #pragma unroll
        for (int n0 = 0; n0 < 8; ++n0) {
            atomicAdd(&R[n0 * 16 + m], s[n0]);
            atomicAdd(&R[128 + n0 * 16 + m], s2[n0]);
        }
    }
}

__global__ void k_bnfinalize(const float* __restrict__ Srep,
    const float* __restrict__ gamma, const float* __restrict__ beta,
    float* __restrict__ SC, int M)
{
    int f = threadIdx.x;   // 128
    float s = 0.f, s2 = 0.f;
    for (int r = 0; r < NREP; ++r) {
        s += Srep[r * 256 + f];
        s2 += Srep[r * 256 + 128 + f];
    }
    float mean = s / (float)M;
    float var = s2 / (float)M - mean * mean;
    var = fmaxf(var, 0.f);
    float sc = gamma[f] * rsqrtf(var + BN_EPS);
    SC[f] = sc;
    SC[HID + f] = beta[f] - mean * sc;
}

// ---------------- pooling (fused BN+ReLU) ----------------
__global__ void k_bounds(const int* __restrict__ batch, int* __restrict__ gstart)
{
    int g = threadIdx.x;
    int lo = 0, hi = N_NODES;
    while (lo < hi) {
        int mid = (lo + hi) >> 1;
        if (batch[mid] < g) lo = mid + 1; else hi = mid;
    }
    gstart[g] = lo;
    if (g == 0) gstart[NGRAPH] = N_NODES;
}

__global__ __launch_bounds__(256) void k_pool(const unsigned short* __restrict__ H,
    const float* __restrict__ SC, const int* __restrict__ gstart,
    float* __restrict__ P)
{
    int g = blockIdx.x >> 4, part = blockIdx.x & 15;
    int beg = gstart[g], end = gstart[g + 1];
    int f = threadIdx.x & 127, half = threadIdx.x >> 7;
    float sc = SC[f], sh = SC[HID + f];
    float s = 0.f;
    for (int r = beg + part * 2 + half; r < end; r += 32)
        s += fmaxf(b2f(H[(size_t)r * HID + f]) * sc + sh, 0.f);
    __shared__ float ls[256];
    ls[threadIdx.x] = s;
    __syncthreads();
    if (threadIdx.x < 128)
        atomicAdd(&P[g * HID + threadIdx.x], ls[threadIdx.x] + ls[threadIdx.x + 128]);
}

// ---------------- classifier head + log_softmax ----------------
__global__ void k_head(const float* __restrict__ P, const int* __restrict__ gstart,
    const float* __restrict__ Wlin, const float* __restrict__ blin,
    float* __restrict__ out)
{
    int g = blockIdx.x;
    int l = threadIdx.x;    // 64 lanes
    float inv = 1.f / (float)max(gstart[g + 1] - gstart[g], 1);
    float p0 = P[(size_t)g * HID + l] * inv;
    float p1 = P[(size_t)g * HID + 64 + l] * inv;
    float lg[10];
    #pragma unroll
    for (int c = 0; c < 10; ++c) {
        float v = p0 * Wlin[l * 10 + c] + p1 * Wlin[(64 + l) * 10 + c];
        #pragma unroll
        for (int off = 32; off > 0; off >>= 1) v += __shfl_down(v, off);
        lg[c] = v;
    }
    if (l == 0) {
        float mx = -1e30f;
        #pragma unroll
        for (int c = 0; c < 10; ++c) { lg[c] += blin[c]; mx = fmaxf(mx, lg[c]); }
        float s = 0.f;
        #pragma unroll
        for (int c = 0; c < 10; ++c) s += expf(lg[c] - mx);
        float lse = mx + logf(s);
        #pragma unroll
        for (int c = 0; c < 10; ++c) out[g * 10 + c] = lg[c] - lse;
    }
}

extern "C" void kernel_launch(void* const* d_in, const int* in_sizes, int n_in,
                              void* d_out, int out_size, void* d_ws, size_t ws_size,
                              hipStream_t stream)
{
    const float* x    = (const float*)d_in[0];
    const int*   ei   = (const int*)d_in[1];
    const int*   batch= (const int*)d_in[2];
    const float* W1a  = (const float*)d_in[3];
    const float* b1a  = (const float*)d_in[4];
    const float* W1b  = (const float*)d_in[5];
    const float* b1b  = (const float*)d_in[6];
    const float* g1   = (const float*)d_in[7];
    const float* be1  = (const float*)d_in[8];
    const float* W2a  = (const float*)d_in[9];
    const float* b2a  = (const float*)d_in[10];
    const float* W2b  = (const float*)d_in[11];
    const float* b2b  = (const float*)d_in[12];
    const float* g2   = (const float*)d_in[13];
    const float* be2  = (const float*)d_in[14];
    const float* Wl   = (const float*)d_in[15];
    const float* bl   = (const float*)d_in[16];
    float* out = (float*)d_out;

    const int* src = ei;
    const int* dst = ei + N_EDGESC;

    const size_t NM = (size_t)N_NODES * HID;    // 12.8M
    char* wsb = (char*)d_ws;
    // Ab first: k_mlp overreads 32 rows past Ab -> lands in Yb (valid).
    unsigned short* Ab  = (unsigned short*)wsb;                 // NM u16 (agg out)
    unsigned short* Yb  = Ab + NM;                              // NM u16 (Cb1)
    unsigned short* Xb  = Yb + NM;                              // NM u16 (x / Cb2)
    float* Srep1 = (float*)(Xb + NM);                           // NREP*256
    float* Srep2 = Srep1 + NREP * 256;                          // NREP*256
    float* SC1  = Srep2 + NREP * 256;                           // 256
    float* SC2  = SC1 + 256;                                    // 256
    float* P    = SC2 + 256;                                    // 128*128
    unsigned short* WT = (unsigned short*)(P + (size_t)NGRAPH * HID); // 4*16384 u16
    int* deg    = (int*)(WT + 4 * 16384);
    int* off    = deg + N_NODES;
    int* cursor = off + N_NODES + 1;
    int* bsum   = cursor + N_NODES;
    int* eidx   = bsum + SCAN_BLOCKS;
    int* gstart = eidx + N_EDGESC;

    dim3 blk(256);
    const int edgeBlocks = (N_EDGESC + 255) / 256;     // 3125
    const int nodeBlocks = (N_NODES + 255) / 256;      // 391
    const int mlpBlocks  = (N_NODES + 63) / 64;        // 1563
    const int gatBlocks  = (N_NODES + 15) / 16;        // 6250
    const int cvtBlocks = (int)(NM / 4 + 255) / 256;   // 12500

    // ---- CSR build + conversions ----
    hipMemsetAsync(deg, 0, N_NODES * sizeof(int), stream);
    hipMemsetAsync(P, 0, (size_t)NGRAPH * HID * sizeof(float), stream);
    hipMemsetAsync(Srep1, 0, 2 * NREP * 256 * sizeof(float), stream);
    k_count<<<edgeBlocks, blk, 0, stream>>>(dst, deg);
    k_scan_block<<<SCAN_BLOCKS, blk, 0, stream>>>(deg, off, bsum);
    k_scan_top<<<1, 1, 0, stream>>>(bsum, off);
    k_scan_add<<<nodeBlocks, blk, 0, stream>>>(off, bsum, cursor);
    k_fill<<<edgeBlocks, blk, 0, stream>>>(src, dst, cursor, eidx);
    k_bounds<<<1, 128, 0, stream>>>(batch, gstart);
    k_cvt<<<cvtBlocks, blk, 0, stream>>>(x, Xb, (int)(NM / 4));
    k_wcvt4<<<256, blk, 0, stream>>>(W1a, W1b, W2a, W2b, WT);

    // ---- conv1 ----
    k_gather<false><<<gatBlocks, blk, 0, stream>>>(Xb, nullptr, off, eidx, Ab, N_NODES);
    k_mlp<<<mlpBlocks, blk, 0, stream>>>(Ab, WT, b1a, WT + 16384, b1b, Yb, Srep1, N_NODES);
    k_bnfinalize<<<1, 128, 0, stream>>>(Srep1, g1, be1, SC1, N_NODES);

    // ---- conv2 (BN1+ReLU fused into gather) ----
    k_gather<true><<<gatBlocks, blk, 0, stream>>>(Yb, SC1, off, eidx, Ab, N_NODES);
    k_mlp<<<mlpBlocks, blk, 0, stream>>>(Ab, WT + 2 * 16384, b2a, WT + 3 * 16384, b2b, Xb, Srep2, N_NODES);
    k_bnfinalize<<<1, 128, 0, stream>>>(Srep2, g2, be2, SC2, N_NODES);

    // ---- pool (BN2+ReLU fused) + head ----
    k_pool<<<NGRAPH * 16, blk, 0, stream>>>(Xb, SC2, gstart, P);
    k_head<<<NGRAPH, 64, 0, stream>>>(P, gstart, Wl, bl, out);
}

// Round 7
// 402.895 us; speedup vs baseline: 9.4631x; 1.1082x over previous
//
#include <hip/hip_runtime.h>

#define N_NODES 100000
#define N_EDGESC 800000
#define HID 128
#define NGRAPH 128
#define BN_EPS 1e-5f
#define SCAN_BLOCKS ((N_NODES + 1023) / 1024)   // 98
#define NREP 32   // BN-stats atomic replicas
#define PS 136    // LDS row stride in shorts: 272B = 16B-aligned
#define MLP_GRID 521   // 1563 tiles / 521 = exactly 3 per block

typedef __bf16 bf16x8 __attribute__((ext_vector_type(8)));
typedef float f32x4 __attribute__((ext_vector_type(4)));

__device__ inline unsigned short f2bf(float f) {     // RNE fp32 -> bf16
    unsigned int u = __float_as_uint(f);
    unsigned int r = u + 0x7FFFu + ((u >> 16) & 1u);
    return (unsigned short)(r >> 16);
}
__device__ inline float b2f(unsigned short u) {
    return __uint_as_float(((unsigned int)u) << 16);
}

// ================= CSR build =================
__global__ __launch_bounds__(256) void k_count(const int* __restrict__ dst,
                                               int* __restrict__ deg)
{
    int e = blockIdx.x * 256 + threadIdx.x;
    if (e < N_EDGESC) atomicAdd(&deg[dst[e]], 1);
}

__global__ __launch_bounds__(256) void k_scan_block(const int* __restrict__ deg,
    int* __restrict__ off, int* __restrict__ bsum)
{
    __shared__ int ts[256];
    int base = blockIdx.x * 1024 + threadIdx.x * 4;
    int v[4], s = 0;
    #pragma unroll
    for (int i = 0; i < 4; ++i) {
        int idx = base + i;
        v[i] = (idx < N_NODES) ? deg[idx] : 0;
        s += v[i];
    }
    ts[threadIdx.x] = s;
    __syncthreads();
    for (int d = 1; d < 256; d <<= 1) {
        int t = (threadIdx.x >= d) ? ts[threadIdx.x - d] : 0;
        __syncthreads();
        ts[threadIdx.x] += t;
        __syncthreads();
    }
    int run = ts[threadIdx.x] - s;
    #pragma unroll
    for (int i = 0; i < 4; ++i) {
        int idx = base + i;
        if (idx < N_NODES) off[idx] = run;
        run += v[i];
    }
    if (threadIdx.x == 255) bsum[blockIdx.x] = ts[255];
}

__global__ void k_scan_top(int* __restrict__ bsum, int* __restrict__ off)
{
    int run = 0;
    for (int i = 0; i < SCAN_BLOCKS; ++i) { int t = bsum[i]; bsum[i] = run; run += t; }
    off[N_NODES] = run;
}

__global__ __launch_bounds__(256) void k_scan_add(int* __restrict__ off,
    const int* __restrict__ bsum, int* __restrict__ cursor)
{
    int i = blockIdx.x * 256 + threadIdx.x;
    if (i < N_NODES) {
        int o = off[i] + bsum[i >> 10];
        off[i] = o;
        cursor[i] = o;
    }
}

__global__ __launch_bounds__(256) void k_fill(const int* __restrict__ src,
    const int* __restrict__ dst, int* __restrict__ cursor, int* __restrict__ eidx)
{
    int e = blockIdx.x * 256 + threadIdx.x;
    if (e < N_EDGESC) {
        int p = atomicAdd(&cursor[dst[e]], 1);
        eidx[p] = src[e];
    }
}

// ================ dtype conversion ================
__global__ __launch_bounds__(256) void k_cvt(const float* __restrict__ X,
    unsigned short* __restrict__ Y, int n4)
{
    int i = blockIdx.x * 256 + threadIdx.x;
    if (i < n4) {
        float4 v = ((const float4*)X)[i];
        ((ushort4*)Y)[i] = make_ushort4(f2bf(v.x), f2bf(v.y), f2bf(v.z), f2bf(v.w));
    }
}

__global__ __launch_bounds__(256) void k_wcvt4(const float* __restrict__ Wa,
    const float* __restrict__ Wb, const float* __restrict__ Wc,
    const float* __restrict__ Wd, unsigned short* __restrict__ WT)
{
    int idx = blockIdx.x * 256 + threadIdx.x;   // 256 blocks -> 65536
    int mat = idx >> 14, w = idx & 16383;
    int k = w >> 7, n = w & 127;
    const float* W = (mat == 0) ? Wa : (mat == 1) ? Wb : (mat == 2) ? Wc : Wd;
    WT[mat * 16384 + n * 128 + k] = f2bf(W[w]);
}

// ================ gather: OUT[n] = f(X[n]) + sum f(X[j]) ================
// 16 lanes per node, uint4 = 8 bf16 (16B) per lane; 8-way edge ILP.
template<bool BN>
__device__ inline void acc_row(float* acc, uint4 v,
                               const float* sc, const float* sh)
{
    unsigned int u[4] = {v.x, v.y, v.z, v.w};
    #pragma unroll
    for (int j = 0; j < 4; ++j) {
        float lo = b2f((unsigned short)u[j]);
        float hi = b2f((unsigned short)(u[j] >> 16));
        if (BN) {
            lo = fmaxf(lo * sc[2*j]   + sh[2*j],   0.f);
            hi = fmaxf(hi * sc[2*j+1] + sh[2*j+1], 0.f);
        }
        acc[2*j]   += lo;
        acc[2*j+1] += hi;
    }
}

template<bool BN>
__global__ __launch_bounds__(256) void k_gather(
    const unsigned short* __restrict__ X, const float* __restrict__ SC,
    const int* __restrict__ off, const int* __restrict__ eidx,
    unsigned short* __restrict__ OUT, int M)
{
    int n = blockIdx.x * 16 + (threadIdx.x >> 4);
    if (n >= M) return;
    const int lane = threadIdx.x & 15;
    const size_t co = (size_t)lane * 8;

    float sc[8], sh[8];
    if (BN) {
        *(float4*)&sc[0] = ((const float4*)SC)[lane * 2];
        *(float4*)&sc[4] = ((const float4*)SC)[lane * 2 + 1];
        *(float4*)&sh[0] = ((const float4*)SC)[32 + lane * 2];
        *(float4*)&sh[4] = ((const float4*)SC)[32 + lane * 2 + 1];
    }

    float acc[8] = {0.f, 0.f, 0.f, 0.f, 0.f, 0.f, 0.f, 0.f};
    acc_row<BN>(acc, *(const uint4*)(X + (size_t)n * HID + co), sc, sh);

    int k = off[n], kend = off[n + 1];
    for (; k + 7 < kend; k += 8) {       // 8-way ILP: 128B in flight per lane
        uint4 v0 = *(const uint4*)(X + (size_t)eidx[k]   * HID + co);
        uint4 v1 = *(const uint4*)(X + (size_t)eidx[k+1] * HID + co);
        uint4 v2 = *(const uint4*)(X + (size_t)eidx[k+2] * HID + co);
        uint4 v3 = *(const uint4*)(X + (size_t)eidx[k+3] * HID + co);
        uint4 v4 = *(const uint4*)(X + (size_t)eidx[k+4] * HID + co);
        uint4 v5 = *(const uint4*)(X + (size_t)eidx[k+5] * HID + co);
        uint4 v6 = *(const uint4*)(X + (size_t)eidx[k+6] * HID + co);
        uint4 v7 = *(const uint4*)(X + (size_t)eidx[k+7] * HID + co);
        acc_row<BN>(acc, v0, sc, sh); acc_row<BN>(acc, v1, sc, sh);
        acc_row<BN>(acc, v2, sc, sh); acc_row<BN>(acc, v3, sc, sh);
        acc_row<BN>(acc, v4, sc, sh); acc_row<BN>(acc, v5, sc, sh);
        acc_row<BN>(acc, v6, sc, sh); acc_row<BN>(acc, v7, sc, sh);
    }
    for (; k + 3 < kend; k += 4) {
        uint4 v0 = *(const uint4*)(X + (size_t)eidx[k]   * HID + co);
        uint4 v1 = *(const uint4*)(X + (size_t)eidx[k+1] * HID + co);
        uint4 v2 = *(const uint4*)(X + (size_t)eidx[k+2] * HID + co);
        uint4 v3 = *(const uint4*)(X + (size_t)eidx[k+3] * HID + co);
        acc_row<BN>(acc, v0, sc, sh); acc_row<BN>(acc, v1, sc, sh);
        acc_row<BN>(acc, v2, sc, sh); acc_row<BN>(acc, v3, sc, sh);
    }
    for (; k < kend; ++k) {
        uint4 v = *(const uint4*)(X + (size_t)eidx[k] * HID + co);
        acc_row<BN>(acc, v, sc, sh);
    }

    uint4 o;
    o.x = (unsigned int)f2bf(acc[0]) | ((unsigned int)f2bf(acc[1]) << 16);
    o.y = (unsigned int)f2bf(acc[2]) | ((unsigned int)f2bf(acc[3]) << 16);
    o.z = (unsigned int)f2bf(acc[4]) | ((unsigned int)f2bf(acc[5]) << 16);
    o.w = (unsigned int)f2bf(acc[6]) | ((unsigned int)f2bf(acc[7]) << 16);
    *(uint4*)(OUT + (size_t)n * HID + co) = o;
}

// ============== persistent fused MLP with cross-tile prefetch ==============
// Grid-stride over 64-row tiles (3 per block). Wave-private LDS; NO barriers
// (barriers would force vmcnt(0) drain, killing the A-prefetch). Same-wave
// DS write->read ordering is guaranteed (aliasing dep + in-order DS pipe).
__global__ __launch_bounds__(256) void k_mlp(
    const unsigned short* __restrict__ A,
    const unsigned short* __restrict__ WTa, const float* __restrict__ ba,
    const unsigned short* __restrict__ WTb, const float* __restrict__ bb,
    unsigned short* __restrict__ Cb, float* __restrict__ Srep, int M)
{
    __shared__ unsigned short Hs[4][16 * PS];

    const int tid = threadIdx.x;
    const int wave = tid >> 6;
    const int lane = tid & 63;
    const int m = lane & 15;
    const int quad = lane >> 4;
    unsigned short* lds = Hs[wave];
    const int ntiles = (M + 63) / 64;

    // hoisted biases (per-lane feature m)
    float bav[8], bbv[8];
    #pragma unroll
    for (int n0 = 0; n0 < 8; ++n0) { bav[n0] = ba[n0*16+m]; bbv[n0] = bb[n0*16+m]; }

    // cross-tile BN-stat accumulators
    float s[8] = {0,0,0,0,0,0,0,0}, s2[8] = {0,0,0,0,0,0,0,0};

    int t = blockIdx.x;
    bf16x8 aN[4];
    if (t < ntiles) {
        const unsigned short* arow = A + (size_t)(t*64 + wave*16 + m) * HID + quad*8;
        #pragma unroll
        for (int kk = 0; kk < 4; ++kk) aN[kk] = *(const bf16x8*)(arow + kk*32);
    }

    for (; t < ntiles; t += MLP_GRID) {
        bf16x8 a[4];
        #pragma unroll
        for (int kk = 0; kk < 4; ++kk) a[kk] = aN[kk];

        int tn = t + MLP_GRID;               // prefetch next tile's A-frags
        if (tn < ntiles) {
            const unsigned short* arow = A + (size_t)(tn*64 + wave*16 + m) * HID + quad*8;
            #pragma unroll
            for (int kk = 0; kk < 4; ++kk) aN[kk] = *(const bf16x8*)(arow + kk*32);
        }

        // ---- GEMM-a ----
        f32x4 acc[8];
        #pragma unroll
        for (int n0 = 0; n0 < 8; ++n0) acc[n0] = {0.f, 0.f, 0.f, 0.f};
        #pragma unroll
        for (int kk = 0; kk < 4; ++kk) {
            #pragma unroll
            for (int n0 = 0; n0 < 8; ++n0) {
                bf16x8 b = *(const bf16x8*)(WTa + (size_t)(n0*16+m)*HID + quad*8 + kk*32);
                acc[n0] = __builtin_amdgcn_mfma_f32_16x16x32_bf16(a[kk], b, acc[n0], 0, 0, 0);
            }
        }

        // hidden = relu(acc + bias) -> wave-private LDS
        #pragma unroll
        for (int n0 = 0; n0 < 8; ++n0)
            #pragma unroll
            for (int r = 0; r < 4; ++r)
                lds[(quad*4+r)*PS + n0*16+m] = f2bf(fmaxf(acc[n0][r] + bav[n0], 0.f));
        __builtin_amdgcn_sched_barrier(0);

        bf16x8 hfr[4];
        #pragma unroll
        for (int kk = 0; kk < 4; ++kk)
            hfr[kk] = *(const bf16x8*)(lds + m*PS + quad*8 + kk*32);
        __builtin_amdgcn_sched_barrier(0);

        // ---- GEMM-b ----
        #pragma unroll
        for (int n0 = 0; n0 < 8; ++n0) acc[n0] = {0.f, 0.f, 0.f, 0.f};
        #pragma unroll
        for (int kk = 0; kk < 4; ++kk) {
            #pragma unroll
            for (int n0 = 0; n0 < 8; ++n0) {
                bf16x8 b = *(const bf16x8*)(WTb + (size_t)(n0*16+m)*HID + quad*8 + kk*32);
                acc[n0] = __builtin_amdgcn_mfma_f32_16x16x32_bf16(hfr[kk], b, acc[n0], 0, 0, 0);
            }
        }

        // ---- epilogue: bias, stats, bf16 -> LDS, coalesced store ----
        const int rowbase = t*64 + wave*16;
        bool full = (rowbase + 16 <= M);
        #pragma unroll
        for (int n0 = 0; n0 < 8; ++n0) {
            #pragma unroll
            for (int r = 0; r < 4; ++r) {
                float v = acc[n0][r] + bbv[n0];
                if (full || rowbase + quad*4 + r < M) { s[n0] += v; s2[n0] += v*v; }
                lds[(quad*4+r)*PS + n0*16+m] = f2bf(v);
            }
        }
        __builtin_amdgcn_sched_barrier(0);
        #pragma unroll
        for (int it = 0; it < 4; ++it) {
            int idx = it*64 + lane;
            int row = idx >> 4, chunk = idx & 15;
            uint4 v = *(const uint4*)(lds + row*PS + chunk*8);
            int g = rowbase + row;
            if (g < M) *(uint4*)(Cb + (size_t)g*HID + chunk*8) = v;
        }
        __builtin_amdgcn_sched_barrier(0);
    }

    // ---- once per block: reduce stats over quads, atomics into replicas ----
    #pragma unroll
    for (int n0 = 0; n0 < 8; ++n0) {
        s[n0]  += __shfl_xor(s[n0], 16, 64);
        s[n0]  += __shfl_xor(s[n0], 32, 64);
        s2[n0] += __shfl_xor(s2[n0], 16, 64);
        s2[n0] += __shfl_xor(s2[n0], 32, 64);
    }
    if (quad == 0) {
        float* R = Srep + (size_t)((blockIdx.x * 4 + wave) & (NREP - 1)) * 256;
        #pragma unroll
        for (int n0 = 0; n0 < 8; ++n0) {
            atomicAdd(&R[n0*16+m], s[n0]);
            atomicAdd(&R[128 + n0*16+m], s2[n0]);
        }
    }
}

__global__ void k_bnfinalize(const float* __restrict__ Srep,
    const float* __restrict__ gamma, const float* __restrict__ beta,
    float* __restrict__ SC, int M)
{
    int f = threadIdx.x;   // 128
    float s = 0.f, s2 = 0.f;
    for (int r = 0; r < NREP; ++r) {
        s += Srep[r * 256 + f];
        s2 += Srep[r * 256 + 128 + f];
    }
    float mean = s / (float)M;
    float var = s2 / (float)M - mean * mean;
    var = fmaxf(var, 0.f);
    float sc = gamma[f] * rsqrtf(var + BN_EPS);
    SC[f] = sc;
    SC[HID + f] = beta[f] - mean * sc;
}

// ---------------- pooling (fused BN+ReLU) ----------------
__global__ void k_bounds(const int* __restrict__ batch, int* __restrict__ gstart)
{
    int g = threadIdx.x;
    int lo = 0, hi = N_NODES;
    while (lo < hi) {
        int mid = (lo + hi) >> 1;
        if (batch[mid] < g) lo = mid + 1; else hi = mid;
    }
    gstart[g] = lo;
    if (g == 0) gstart[NGRAPH] = N_NODES;
}

__global__ __launch_bounds__(256) void k_pool(const unsigned short* __restrict__ H,
    const float* __restrict__ SC, const int* __restrict__ gstart,
    float* __restrict__ P)
{
    int g = blockIdx.x >> 4, part = blockIdx.x & 15;
    int beg = gstart[g], end = gstart[g + 1];
    int f = threadIdx.x & 127, half = threadIdx.x >> 7;
    float sc = SC[f], sh = SC[HID + f];
    float s = 0.f;
    for (int r = beg + part * 2 + half; r < end; r += 32)
        s += fmaxf(b2f(H[(size_t)r * HID + f]) * sc + sh, 0.f);
    __shared__ float ls[256];
    ls[threadIdx.x] = s;
    __syncthreads();
    if (threadIdx.x < 128)
        atomicAdd(&P[g * HID + threadIdx.x], ls[threadIdx.x] + ls[threadIdx.x + 128]);
}

// ---------------- classifier head + log_softmax ----------------
__global__ void k_head(const float* __restrict__ P, const int* __restrict__ gstart,
    const float* __restrict__ Wlin, const float* __restrict__ blin,
    float* __restrict__ out)
{
    int g = blockIdx.x;
    int l = threadIdx.x;    // 64 lanes
    float inv = 1.f / (float)max(gstart[g + 1] - gstart[g], 1);
    float p0 = P[(size_t)g * HID + l] * inv;
    float p1 = P[(size_t)g * HID + 64 + l] * inv;
    float lg[10];
    #pragma unroll
    for (int c = 0; c < 10; ++c) {
        float v = p0 * Wlin[l * 10 + c] + p1 * Wlin[(64 + l) * 10 + c];
        #pragma unroll
        for (int off = 32; off > 0; off >>= 1) v += __shfl_down(v, off);
        lg[c] = v;
    }
    if (l == 0) {
        float mx = -1e30f;
        #pragma unroll
        for (int c = 0; c < 10; ++c) { lg[c] += blin[c]; mx = fmaxf(mx, lg[c]); }
        float s = 0.f;
        #pragma unroll
        for (int c = 0; c < 10; ++c) s += expf(lg[c] - mx);
        float lse = mx + logf(s);
        #pragma unroll
        for (int c = 0; c < 10; ++c) out[g * 10 + c] = lg[c] - lse;
    }
}

extern "C" void kernel_launch(void* const* d_in, const int* in_sizes, int n_in,
                              void* d_out, int out_size, void* d_ws, size_t ws_size,
                              hipStream_t stream)
{
    const float* x    = (const float*)d_in[0];
    const int*   ei   = (const int*)d_in[1];
    const int*   batch= (const int*)d_in[2];
    const float* W1a  = (const float*)d_in[3];
    const float* b1a  = (const float*)d_in[4];
    const float* W1b  = (const float*)d_in[5];
    const float* b1b  = (const float*)d_in[6];
    const float* g1   = (const float*)d_in[7];
    const float* be1  = (const float*)d_in[8];
    const float* W2a  = (const float*)d_in[9];
    const float* b2a  = (const float*)d_in[10];
    const float* W2b  = (const float*)d_in[11];
    const float* b2b  = (const float*)d_in[12];
    const float* g2   = (const float*)d_in[13];
    const float* be2  = (const float*)d_in[14];
    const float* Wl   = (const float*)d_in[15];
    const float* bl   = (const float*)d_in[16];
    float* out = (float*)d_out;

    const int* src = ei;
    const int* dst = ei + N_EDGESC;

    const size_t NM = (size_t)N_NODES * HID;    // 12.8M
    char* wsb = (char*)d_ws;
    // Ab first: k_mlp overreads 32 rows past Ab -> lands in Yb (valid).
    unsigned short* Ab  = (unsigned short*)wsb;                 // NM u16 (agg out)
    unsigned short* Yb  = Ab + NM;                              // NM u16 (Cb1)
    unsigned short* Xb  = Yb + NM;                              // NM u16 (x / Cb2)
    float* Srep1 = (float*)(Xb + NM);                           // NREP*256
    float* Srep2 = Srep1 + NREP * 256;                          // NREP*256
    float* SC1  = Srep2 + NREP * 256;                           // 256
    float* SC2  = SC1 + 256;                                    // 256
    float* P    = SC2 + 256;                                    // 128*128
    unsigned short* WT = (unsigned short*)(P + (size_t)NGRAPH * HID); // 4*16384 u16
    int* deg    = (int*)(WT + 4 * 16384);
    int* off    = deg + N_NODES;
    int* cursor = off + N_NODES + 1;
    int* bsum   = cursor + N_NODES;
    int* eidx   = bsum + SCAN_BLOCKS;
    int* gstart = eidx + N_EDGESC;

    dim3 blk(256);
    const int edgeBlocks = (N_EDGESC + 255) / 256;     // 3125
    const int nodeBlocks = (N_NODES + 255) / 256;      // 391
    const int gatBlocks  = (N_NODES + 15) / 16;        // 6250
    const int cvtBlocks = (int)(NM / 4 + 255) / 256;   // 12500

    // ---- CSR build + conversions ----
    hipMemsetAsync(deg, 0, N_NODES * sizeof(int), stream);
    hipMemsetAsync(P, 0, (size_t)NGRAPH * HID * sizeof(float), stream);
    hipMemsetAsync(Srep1, 0, 2 * NREP * 256 * sizeof(float), stream);
    k_count<<<edgeBlocks, blk, 0, stream>>>(dst, deg);
    k_scan_block<<<SCAN_BLOCKS, blk, 0, stream>>>(deg, off, bsum);
    k_scan_top<<<1, 1, 0, stream>>>(bsum, off);
    k_scan_add<<<nodeBlocks, blk, 0, stream>>>(off, bsum, cursor);
    k_fill<<<edgeBlocks, blk, 0, stream>>>(src, dst, cursor, eidx);
    k_bounds<<<1, 128, 0, stream>>>(batch, gstart);
    k_cvt<<<cvtBlocks, blk, 0, stream>>>(x, Xb, (int)(NM / 4));
    k_wcvt4<<<256, blk, 0, stream>>>(W1a, W1b, W2a, W2b, WT);

    // ---- conv1 ----
    k_gather<false><<<gatBlocks, blk, 0, stream>>>(Xb, nullptr, off, eidx, Ab, N_NODES);
    k_mlp<<<MLP_GRID, blk, 0, stream>>>(Ab, WT, b1a, WT + 16384, b1b, Yb, Srep1, N_NODES);
    k_bnfinalize<<<1, 128, 0, stream>>>(Srep1, g1, be1, SC1, N_NODES);

    // ---- conv2 (BN1+ReLU fused into gather) ----
    k_gather<true><<<gatBlocks, blk, 0, stream>>>(Yb, SC1, off, eidx, Ab, N_NODES);
    k_mlp<<<MLP_GRID, blk, 0, stream>>>(Ab, WT + 2 * 16384, b2a, WT + 3 * 16384, b2b, Xb, Srep2, N_NODES);
    k_bnfinalize<<<1, 128, 0, stream>>>(Srep2, g2, be2, SC2, N_NODES);

    // ---- pool (BN2+ReLU fused) + head ----
    k_pool<<<NGRAPH * 16, blk, 0, stream>>>(Xb, SC2, gstart, P);
    k_head<<<NGRAPH, 64, 0, stream>>>(P, gstart, Wl, bl, out);
}